// Round 3
// baseline (288.020 us; speedup 1.0000x reference)
//
#include <hip/hip_runtime.h>
#include <type_traits>

// GraphSAGE 2-layer, N=100k, C 128->128->64, E=1.6M, fp32 in/out.
// R8: pre-transposed bf16 W (k_wprep) -> conflict-free GEMM B-staging.
// R9: latency-optimized aggregation (4 edges per VMEM instr).
// R10: quarter-per-node aggregation (no cross-lane reduce, full-wave epilogue).
// R11: fused-panel GEMM — A staged ONCE per tile, both Wl/Wr products
// computed in the same block (halves X HBM reads + staging VALU); B
// fragments register-loaded from L2 (no B LDS, no extra barrier);
// 4 wprep launches fused into 1.

constexpr int K = 128;
constexpr int EB = 4096;  // edges per partition block

typedef __bf16 bf16x2 __attribute__((ext_vector_type(2)));
typedef __bf16 bf16x4 __attribute__((ext_vector_type(4)));
typedef __bf16 bf16x8 __attribute__((ext_vector_type(8)));
typedef float f32x4 __attribute__((ext_vector_type(4)));
typedef float f32x2 __attribute__((ext_vector_type(2)));

// ---------------- fp8 e4m3 conversion ----------------

__device__ __forceinline__ unsigned char to_fp8(float v) {
#if __has_builtin(__builtin_amdgcn_cvt_pk_fp8_f32)
  int p = __builtin_amdgcn_cvt_pk_fp8_f32(v, v, 0, false);
  return (unsigned char)(p & 0xff);
#else
  unsigned u = __builtin_bit_cast(unsigned, v);
  unsigned s = (u >> 24) & 0x80u;
  float a = fabsf(v);
  if (a > 448.f) a = 448.f;
  unsigned bits;
  if (a < 0.015625f) {
    bits = (unsigned)(a * 512.f + 0.5f);
  } else {
    unsigned b = __builtin_bit_cast(unsigned, a);
    b += ((b >> 20) & 1) + 0x0007FFFF;
    unsigned e = (b >> 23) - 120;
    bits = (e << 3) | ((b >> 20) & 7);
    if (bits > 0x7E) bits = 0x7E;
  }
  return (unsigned char)(s | bits);
#endif
}

__device__ __forceinline__ f32x2 from_fp8x2(unsigned short u) {
#if __has_builtin(__builtin_amdgcn_cvt_pk_f32_fp8)
  return __builtin_amdgcn_cvt_pk_f32_fp8((int)u, false);
#else
  f32x2 r;
  unsigned b0 = u & 0xff, b1 = (u >> 8) & 0xff;
  unsigned e0 = (b0 >> 3) & 15, m0 = b0 & 7;
  unsigned e1 = (b1 >> 3) & 15, m1 = b1 & 7;
  float v0 = e0 ? __builtin_bit_cast(float, ((e0 + 120) << 23) | (m0 << 20))
              : (float)m0 * 0.001953125f;
  float v1 = e1 ? __builtin_bit_cast(float, ((e1 + 120) << 23) | (m1 << 20))
              : (float)m1 * 0.001953125f;
  r[0] = (b0 & 0x80) ? -v0 : v0;
  r[1] = (b1 & 0x80) ? -v1 : v1;
  return r;
#endif
}

__device__ __forceinline__ f32x2 fp8x2_lo(unsigned v) {
#if __has_builtin(__builtin_amdgcn_cvt_pk_f32_fp8)
  return __builtin_amdgcn_cvt_pk_f32_fp8((int)v, false);
#else
  return from_fp8x2((unsigned short)(v & 0xffffu));
#endif
}

__device__ __forceinline__ f32x2 fp8x2_hi(unsigned v) {
#if __has_builtin(__builtin_amdgcn_cvt_pk_f32_fp8)
  return __builtin_amdgcn_cvt_pk_f32_fp8((int)v, true);
#else
  return from_fp8x2((unsigned short)(v >> 16));
#endif
}

// ---------------- W pre-transpose: fp32 [k][COLS] -> bf16 [c][128] ----------------
// All 4 weight matrices in one launch; block ranges select the matrix.

__global__ __launch_bounds__(256) void k_wprep_all(
    const float* __restrict__ W1l, const float* __restrict__ W1r,
    const float* __restrict__ W2l, const float* __restrict__ W2r,
    __bf16* __restrict__ B1l, __bf16* __restrict__ B1r,
    __bf16* __restrict__ B2l, __bf16* __restrict__ B2r) {
  int b = blockIdx.x;
  const float* W;
  __bf16* Bt;
  int idx;
  bool wide;
  if (b < 64) {
    W = W1l; Bt = B1l; idx = b * 256 + threadIdx.x; wide = true;
  } else if (b < 128) {
    W = W1r; Bt = B1r; idx = (b - 64) * 256 + threadIdx.x; wide = true;
  } else if (b < 160) {
    W = W2l; Bt = B2l; idx = (b - 128) * 256 + threadIdx.x; wide = false;
  } else {
    W = W2r; Bt = B2r; idx = (b - 160) * 256 + threadIdx.x; wide = false;
  }
  int k = wide ? (idx >> 7) : (idx >> 6);
  int c = wide ? (idx & 127) : (idx & 63);
  Bt[c * K + k] = (__bf16)W[idx];  // small scattered 2B writes; L2-resident
}

// ---------------- bucketed CSR build ----------------

__global__ __launch_bounds__(256) void k_bhist(const int* __restrict__ dst,
                                               int* __restrict__ blockHist,
                                               int* __restrict__ bucketTotal,
                                               int E, int n, int nB) {
  extern __shared__ int hist[];
  for (int i = threadIdx.x; i < nB; i += 256) hist[i] = 0;
  __syncthreads();
  int base = blockIdx.x * EB, end = min(base + EB, E);
  for (int e = base + threadIdx.x; e < end; e += 256) {
    int d = dst[e];
    if ((unsigned)d < (unsigned)n) atomicAdd(&hist[d >> 8], 1);
  }
  __syncthreads();
  for (int i = threadIdx.x; i < nB; i += 256) {
    int v = hist[i];
    blockHist[(long)blockIdx.x * nB + i] = v;
    if (v) atomicAdd(&bucketTotal[i], v);
  }
}

__global__ __launch_bounds__(512) void k_btop(const int* __restrict__ bucketTotal,
                                              int* __restrict__ bucketBase,
                                              int* __restrict__ bucketCursor, int nB) {
  __shared__ int sh[512];
  int t = threadIdx.x;
  int s = (t < nB) ? bucketTotal[t] : 0;
  sh[t] = s;
  __syncthreads();
  for (int off = 1; off < 512; off <<= 1) {
    int v = (t >= off) ? sh[t - off] : 0;
    __syncthreads();
    sh[t] += v;
    __syncthreads();
  }
  if (t < nB) {
    int base = sh[t] - s;
    bucketBase[t] = base;
    bucketCursor[t] = base;
    if (t == nB - 1) bucketBase[nB] = sh[t];
  }
}

__global__ __launch_bounds__(256) void k_bscatter(const int* __restrict__ src,
                                                  const int* __restrict__ dst,
                                                  const int* __restrict__ blockHist,
                                                  int* __restrict__ bucketCursor,
                                                  unsigned* __restrict__ recs,
                                                  int E, int n, int nB) {
  extern __shared__ int cur[];
  for (int i = threadIdx.x; i < nB; i += 256) {
    int c = blockHist[(long)blockIdx.x * nB + i];
    cur[i] = c ? atomicAdd(&bucketCursor[i], c) : 0;
  }
  __syncthreads();
  int base = blockIdx.x * EB, end = min(base + EB, E);
  for (int e = base + threadIdx.x; e < end; e += 256) {
    int d = dst[e];
    if ((unsigned)d < (unsigned)n) {
      int s = min(max(src[e], 0), n - 1);
      int pos = atomicAdd(&cur[d >> 8], 1);
      recs[pos] = ((unsigned)s << 8) | (unsigned)(d & 255);
    }
  }
}

__global__ __launch_bounds__(256) void k_bfill(const unsigned* __restrict__ recs,
                                               const int* __restrict__ bucketBase,
                                               int* __restrict__ rowptr,
                                               int* __restrict__ col, int n, int nB) {
  __shared__ int degl[256];
  __shared__ int incl[256];
  int b = blockIdx.x, t = threadIdx.x;
  int rbeg = bucketBase[b], rend = bucketBase[b + 1];
  degl[t] = 0;
  __syncthreads();
  for (int i = rbeg + t; i < rend; i += 256)
    atomicAdd(&degl[recs[i] & 255], 1);
  __syncthreads();
  incl[t] = degl[t];
  __syncthreads();
  for (int off = 1; off < 256; off <<= 1) {
    int v = (t >= off) ? incl[t - off] : 0;
    __syncthreads();
    incl[t] += v;
    __syncthreads();
  }
  int excl = incl[t] - degl[t];
  int node = b * 256 + t;
  if (node <= n) rowptr[node] = rbeg + excl;
  __syncthreads();
  degl[t] = rbeg + excl;  // reuse as cursor
  __syncthreads();
  for (int i = rbeg + t; i < rend; i += 256) {
    unsigned r = recs[i];
    int pos = atomicAdd(&degl[r & 255], 1);
    col[pos] = (int)(r >> 8);
  }
}

// ---------------- bf16 MFMA GEMM (fused dual-panel) ----------------
// Per block: stage A[64 x 128] ONCE, then compute A@Wl -> fp8 outA and
// A@Wr -> bf16 outB sequentially. B fragments are register-loaded from
// global (weights are 16-32KB, L2-resident after k_wprep_all); no B LDS,
// single barrier. LDS = 64*136*2B = 17.4KB -> high occupancy.

template <int COLS, typename TIN>
__global__ __launch_bounds__(256) void k_gemm_fused(const TIN* __restrict__ X,
                                                    const __bf16* __restrict__ Bta,
                                                    const __bf16* __restrict__ Btb,
                                                    unsigned char* __restrict__ outA,
                                                    __bf16* __restrict__ outB, int nrows) {
  constexpr int LD = 136;
  constexpr int MT_N = COLS / 32;
  __shared__ __bf16 As[64 * LD];

  int tid = threadIdx.x;
  long row0 = (long)blockIdx.x * 64;

  // stage A (convert to bf16 if fp32 input)
  if constexpr (std::is_same_v<TIN, float>) {
#pragma unroll
    for (int it = 0; it < 8; ++it) {
      int i = tid + it * 256;
      int r = i >> 5, c4 = (i & 31) << 2;
      long row = row0 + r;
      float4 v = make_float4(0.f, 0.f, 0.f, 0.f);
      if (row < nrows) v = *(const float4*)(X + row * K + c4);
      bf16x4 bb;
      bb[0] = (__bf16)v.x; bb[1] = (__bf16)v.y; bb[2] = (__bf16)v.z; bb[3] = (__bf16)v.w;
      *(bf16x4*)&As[r * LD + c4] = bb;
    }
  } else {
#pragma unroll
    for (int it = 0; it < 4; ++it) {
      int i = tid + it * 256;
      int r = i >> 4, c8 = (i & 15) << 3;
      long row = row0 + r;
      bf16x8 v = {};
      if (row < nrows) v = *(const bf16x8*)(X + row * K + c8);
      *(bf16x8*)&As[r * LD + c8] = v;
    }
  }
  __syncthreads();

  int w = tid >> 6, lane = tid & 63;
  int m = lane & 15, quad = lane >> 4;
  int wrow = (w >> 1) * 32;
  int wcol = (w & 1) * (COLS / 2);

#pragma unroll
  for (int p = 0; p < 2; ++p) {
    const __bf16* Btg = p ? Btb : Bta;

    f32x4 acc[2][MT_N];
#pragma unroll
    for (int mi = 0; mi < 2; ++mi)
#pragma unroll
      for (int ni = 0; ni < MT_N; ++ni) acc[mi][ni] = (f32x4){0.f, 0.f, 0.f, 0.f};

#pragma unroll
    for (int kc = 0; kc < 4; ++kc) {
      int ko = kc * 32 + quad * 8;
      bf16x8 af[2];
#pragma unroll
      for (int mi = 0; mi < 2; ++mi)
        af[mi] = *(const bf16x8*)&As[(wrow + mi * 16 + m) * LD + ko];
      bf16x8 bfr[MT_N];
#pragma unroll
      for (int ni = 0; ni < MT_N; ++ni)
        bfr[ni] = *(const bf16x8*)(Btg + (long)(wcol + ni * 16 + m) * K + ko);
#pragma unroll
      for (int mi = 0; mi < 2; ++mi)
#pragma unroll
        for (int ni = 0; ni < MT_N; ++ni)
          acc[mi][ni] = __builtin_amdgcn_mfma_f32_16x16x32_bf16(af[mi], bfr[ni], acc[mi][ni], 0, 0, 0);
    }

#pragma unroll
    for (int mi = 0; mi < 2; ++mi) {
#pragma unroll
      for (int r = 0; r < 4; ++r) {
        long grow = row0 + wrow + mi * 16 + quad * 4 + r;
        if (grow < nrows) {
#pragma unroll
          for (int ni = 0; ni < MT_N; ++ni) {
            long idx = grow * COLS + wcol + ni * 16 + m;
            float v = acc[mi][ni][r];
            if (p == 0) outA[idx] = to_fp8(v);
            else        outB[idx] = (__bf16)v;
          }
        }
      }
    }
  }
}

// ---------------- aggregation ----------------
// R10: quarter-per-node. Each 16-lane quarter owns one node; lane l owns
// channels [8l, 8l+8) for ALL edges of that node -> no cross-lane reduce,
// epilogue runs on all 64 lanes (4 nodes simultaneously). Edge indices
// preloaded 16-per-quarter with one coalesced wave load, broadcast
// per-edge via one ds_bpermute (__shfl from same-quarter lane; same exec
// group -> well-defined). 4 edges (one per quarter) per VMEM instruction.

template <bool RELU>
__global__ __launch_bounds__(256) void k_agg128(const unsigned char* __restrict__ Y,
                                                const __bf16* __restrict__ XR,
                                                const float* __restrict__ bias,
                                                const int* __restrict__ rowptr,
                                                const int* __restrict__ col,
                                                __bf16* __restrict__ out, int nnodes) {
  int wave = threadIdx.x >> 6, lane = threadIdx.x & 63;
  int quarter = lane >> 4, l = lane & 15;
  int sb = lane & 48;  // quarter * 16: bpermute source base
  int n = blockIdx.x * 16 + wave * 4 + quarter;
  bool valid = n < nnodes;
  int beg = 0, end = 0;
  if (valid) {
    beg = rowptr[n];
    end = rowptr[n + 1];
  }
  int co = l * 8;  // 8 fp8 channels per lane
  const unsigned char* Yc = Y + co;

  f32x2 av0 = {0.f, 0.f}, av1 = {0.f, 0.f}, av2 = {0.f, 0.f}, av3 = {0.f, 0.f};

  for (int base = beg; base < end; base += 16) {
    int cnt = min(end - base, 16);
    int idx = (l < cnt) ? col[base + l] : 0;  // one coalesced load / 16 edges
    int j = 0;
    for (; j + 3 < cnt; j += 4) {
      long s0 = (unsigned)__shfl(idx, sb + j);
      long s1 = (unsigned)__shfl(idx, sb + j + 1);
      long s2 = (unsigned)__shfl(idx, sb + j + 2);
      long s3 = (unsigned)__shfl(idx, sb + j + 3);
      uint2 v0 = *(const uint2*)(Yc + s0 * 128);
      uint2 v1 = *(const uint2*)(Yc + s1 * 128);
      uint2 v2 = *(const uint2*)(Yc + s2 * 128);
      uint2 v3 = *(const uint2*)(Yc + s3 * 128);
      av0 += fp8x2_lo(v0.x); av1 += fp8x2_hi(v0.x);
      av2 += fp8x2_lo(v0.y); av3 += fp8x2_hi(v0.y);
      av0 += fp8x2_lo(v1.x); av1 += fp8x2_hi(v1.x);
      av2 += fp8x2_lo(v1.y); av3 += fp8x2_hi(v1.y);
      av0 += fp8x2_lo(v2.x); av1 += fp8x2_hi(v2.x);
      av2 += fp8x2_lo(v2.y); av3 += fp8x2_hi(v2.y);
      av0 += fp8x2_lo(v3.x); av1 += fp8x2_hi(v3.x);
      av2 += fp8x2_lo(v3.y); av3 += fp8x2_hi(v3.y);
    }
    for (; j < cnt; ++j) {
      long s = (unsigned)__shfl(idx, sb + j);
      uint2 v = *(const uint2*)(Yc + s * 128);
      av0 += fp8x2_lo(v.x); av1 += fp8x2_hi(v.x);
      av2 += fp8x2_lo(v.y); av3 += fp8x2_hi(v.y);
    }
  }

  if (valid) {
    float inv = 1.f / (float)max(end - beg, 1);
    bf16x8 xv = *(const bf16x8*)(XR + (long)n * 128 + co);
    f32x4 b0 = *(const f32x4*)(bias + co);
    f32x4 b1 = *(const f32x4*)(bias + co + 4);
    float r0 = av0[0] * inv + (float)xv[0] + b0[0];
    float r1 = av0[1] * inv + (float)xv[1] + b0[1];
    float r2 = av1[0] * inv + (float)xv[2] + b0[2];
    float r3 = av1[1] * inv + (float)xv[3] + b0[3];
    float r4 = av2[0] * inv + (float)xv[4] + b1[0];
    float r5 = av2[1] * inv + (float)xv[5] + b1[1];
    float r6 = av3[0] * inv + (float)xv[6] + b1[2];
    float r7 = av3[1] * inv + (float)xv[7] + b1[3];
    if (RELU) {
      r0 = fmaxf(r0, 0.f); r1 = fmaxf(r1, 0.f);
      r2 = fmaxf(r2, 0.f); r3 = fmaxf(r3, 0.f);
      r4 = fmaxf(r4, 0.f); r5 = fmaxf(r5, 0.f);
      r6 = fmaxf(r6, 0.f); r7 = fmaxf(r7, 0.f);
    }
    bf16x8 o;
    o[0] = (__bf16)r0; o[1] = (__bf16)r1; o[2] = (__bf16)r2; o[3] = (__bf16)r3;
    o[4] = (__bf16)r4; o[5] = (__bf16)r5; o[6] = (__bf16)r6; o[7] = (__bf16)r7;
    *(bf16x8*)(out + (long)n * 128 + co) = o;
  }
}

__global__ __launch_bounds__(256) void k_agg64(const unsigned char* __restrict__ Y,
                                               const __bf16* __restrict__ XR,
                                               const float* __restrict__ bias,
                                               const int* __restrict__ rowptr,
                                               const int* __restrict__ col,
                                               float* __restrict__ out, int nnodes) {
  int wave = threadIdx.x >> 6, lane = threadIdx.x & 63;
  int quarter = lane >> 4, l = lane & 15;
  int sb = lane & 48;
  int n = blockIdx.x * 16 + wave * 4 + quarter;
  bool valid = n < nnodes;
  int beg = 0, end = 0;
  if (valid) {
    beg = rowptr[n];
    end = rowptr[n + 1];
  }
  int co = l * 4;  // 4 fp8 channels per lane
  const unsigned char* Yc = Y + co;

  f32x2 av0 = {0.f, 0.f}, av1 = {0.f, 0.f};

  for (int base = beg; base < end; base += 16) {
    int cnt = min(end - base, 16);
    int idx = (l < cnt) ? col[base + l] : 0;
    int j = 0;
    for (; j + 3 < cnt; j += 4) {
      long s0 = (unsigned)__shfl(idx, sb + j);
      long s1 = (unsigned)__shfl(idx, sb + j + 1);
      long s2 = (unsigned)__shfl(idx, sb + j + 2);
      long s3 = (unsigned)__shfl(idx, sb + j + 3);
      unsigned v0 = *(const unsigned*)(Yc + s0 * 64);
      unsigned v1 = *(const unsigned*)(Yc + s1 * 64);
      unsigned v2 = *(const unsigned*)(Yc + s2 * 64);
      unsigned v3 = *(const unsigned*)(Yc + s3 * 64);
      av0 += fp8x2_lo(v0); av1 += fp8x2_hi(v0);
      av0 += fp8x2_lo(v1); av1 += fp8x2_hi(v1);
      av0 += fp8x2_lo(v2); av1 += fp8x2_hi(v2);
      av0 += fp8x2_lo(v3); av1 += fp8x2_hi(v3);
    }
    for (; j < cnt; ++j) {
      long s = (unsigned)__shfl(idx, sb + j);
      unsigned v = *(const unsigned*)(Yc + s * 64);
      av0 += fp8x2_lo(v); av1 += fp8x2_hi(v);
    }
  }

  if (valid) {
    float inv = 1.f / (float)max(end - beg, 1);
    bf16x4 xv = *(const bf16x4*)(XR + (long)n * 64 + co);
    f32x4 bv = *(const f32x4*)(bias + co);
    f32x4 r;
    r[0] = av0[0] * inv + (float)xv[0] + bv[0];
    r[1] = av0[1] * inv + (float)xv[1] + bv[1];
    r[2] = av1[0] * inv + (float)xv[2] + bv[2];
    r[3] = av1[1] * inv + (float)xv[3] + bv[3];
    *(f32x4*)(out + (long)n * 64 + co) = r;
  }
}

// ---------------- launch ----------------

extern "C" void kernel_launch(void* const* d_in, const int* in_sizes, int n_in,
                              void* d_out, int out_size, void* d_ws, size_t ws_size,
                              hipStream_t stream) {
  const float* x   = (const float*)d_in[0];
  const int*   ei  = (const int*)d_in[1];
  const float* W1l = (const float*)d_in[2];
  const float* W1r = (const float*)d_in[3];
  const float* b1  = (const float*)d_in[4];
  const float* W2l = (const float*)d_in[5];
  const float* W2r = (const float*)d_in[6];
  const float* b2  = (const float*)d_in[7];
  float* out = (float*)d_out;

  int N = in_sizes[0] / K;   // 100000
  int E = in_sizes[1] / 2;   // 1600000
  const int* src = ei;
  const int* dst = ei + E;

  int nB = (N + 255) >> 8;          // 391 buckets
  int nblk = (E + EB - 1) / EB;     // 391 partition blocks

  char* ws = (char*)d_ws;
  size_t off = 0;
  auto alloc = [&](size_t bytes) {
    void* p = ws + off;
    off = (off + bytes + 255) & ~(size_t)255;
    return p;
  };
  int*      rowptr       = (int*)alloc(((size_t)N + 2) * 4);
  int*      col          = (int*)alloc((size_t)E * 4);
  int*      blockHist    = (int*)alloc((size_t)nblk * nB * 4);
  int*      bucketTotal  = (int*)alloc(((size_t)nB) * 4);
  int*      bucketBase   = (int*)alloc(((size_t)nB + 1) * 4);
  int*      bucketCursor = (int*)alloc((size_t)nB * 4);
  unsigned* recs         = (unsigned*)alloc((size_t)E * 4);
  unsigned char* y1      = (unsigned char*)alloc((size_t)N * 128);  // fp8
  __bf16*   xr           = (__bf16*)alloc((size_t)N * 128 * 2);
  __bf16*   h            = (__bf16*)alloc((size_t)N * 128 * 2);
  __bf16*   Bt1l         = (__bf16*)alloc((size_t)128 * K * 2);
  __bf16*   Bt1r         = (__bf16*)alloc((size_t)128 * K * 2);
  __bf16*   Bt2l         = (__bf16*)alloc((size_t)64 * K * 2);
  __bf16*   Bt2r         = (__bf16*)alloc((size_t)64 * K * 2);
  unsigned char* y2 = y1;  // layer-1 gather buffer dead after k_agg128; reuse
  __bf16*   hr = xr;

  // W pre-transpose: all 4 matrices, one launch (independent of CSR build)
  k_wprep_all<<<192, 256, 0, stream>>>(W1l, W1r, W2l, W2r, Bt1l, Bt1r, Bt2l, Bt2r);

  // CSR build (bucketed)
  hipMemsetAsync(bucketTotal, 0, (size_t)nB * 4, stream);
  k_bhist<<<nblk, 256, nB * 4, stream>>>(dst, blockHist, bucketTotal, E, N, nB);
  k_btop<<<1, 512, 0, stream>>>(bucketTotal, bucketBase, bucketCursor, nB);
  k_bscatter<<<nblk, 256, nB * 4, stream>>>(src, dst, blockHist, bucketCursor, recs, E, N, nB);
  k_bfill<<<nB, 256, 0, stream>>>(recs, bucketBase, rowptr, col, N, nB);

  int gx = (N + 63) / 64;
  // layer 1: y1 = fp8(x@W1l), xr = bf16(x@W1r); h = relu(mean(y1) + xr + b1)
  k_gemm_fused<128, float><<<gx, 256, 0, stream>>>(x, Bt1l, Bt1r, y1, xr, N);
  k_agg128<true><<<(N + 15) / 16, 256, 0, stream>>>(y1, xr, b1, rowptr, col, h, N);

  // layer 2: y2 = fp8(h@W2l), hr = bf16(h@W2r); out = mean(y2) + hr + b2
  k_gemm_fused<64, __bf16><<<gx, 256, 0, stream>>>(h, Bt2l, Bt2r, y2, hr, N);
  k_agg64<<<(N + 15) / 16, 256, 0, stream>>>(y2, hr, b2, rowptr, col, out, N);
}

// Round 4
// 285.211 us; speedup vs baseline: 1.0098x; 1.0098x over previous
//
#include <hip/hip_runtime.h>
#include <type_traits>

// GraphSAGE 2-layer, N=100k, C 128->128->64, E=1.6M, fp32 in/out.
// R8: pre-transposed bf16 W -> conflict-free GEMM B access.
// R9: latency-optimized aggregation (4 edges per VMEM instr).
// R10: quarter-per-node aggregation (no cross-lane reduce, full-wave epilogue).
// R11: fused-panel GEMM (A staged once for both Wl/Wr products).
// R12: GEMM schedule fix — wave-specialized panels (2 waves Wl, 2 waves Wr),
// ALL B fragments register-preloaded at kernel entry (latency hides under
// A staging + barrier drain); kc loop touches only regs+LDS; launch_bounds
// (256,4) caps VGPR at 128 -> 16 waves/CU (was 24% occupancy, serial
// per-kc L2 round trips).

constexpr int K = 128;
constexpr int EB = 4096;  // edges per partition block

typedef __bf16 bf16x2 __attribute__((ext_vector_type(2)));
typedef __bf16 bf16x4 __attribute__((ext_vector_type(4)));
typedef __bf16 bf16x8 __attribute__((ext_vector_type(8)));
typedef float f32x4 __attribute__((ext_vector_type(4)));
typedef float f32x2 __attribute__((ext_vector_type(2)));

// ---------------- fp8 e4m3 conversion ----------------

__device__ __forceinline__ unsigned char to_fp8(float v) {
#if __has_builtin(__builtin_amdgcn_cvt_pk_fp8_f32)
  int p = __builtin_amdgcn_cvt_pk_fp8_f32(v, v, 0, false);
  return (unsigned char)(p & 0xff);
#else
  unsigned u = __builtin_bit_cast(unsigned, v);
  unsigned s = (u >> 24) & 0x80u;
  float a = fabsf(v);
  if (a > 448.f) a = 448.f;
  unsigned bits;
  if (a < 0.015625f) {
    bits = (unsigned)(a * 512.f + 0.5f);
  } else {
    unsigned b = __builtin_bit_cast(unsigned, a);
    b += ((b >> 20) & 1) + 0x0007FFFF;
    unsigned e = (b >> 23) - 120;
    bits = (e << 3) | ((b >> 20) & 7);
    if (bits > 0x7E) bits = 0x7E;
  }
  return (unsigned char)(s | bits);
#endif
}

__device__ __forceinline__ f32x2 from_fp8x2(unsigned short u) {
#if __has_builtin(__builtin_amdgcn_cvt_pk_f32_fp8)
  return __builtin_amdgcn_cvt_pk_f32_fp8((int)u, false);
#else
  f32x2 r;
  unsigned b0 = u & 0xff, b1 = (u >> 8) & 0xff;
  unsigned e0 = (b0 >> 3) & 15, m0 = b0 & 7;
  unsigned e1 = (b1 >> 3) & 15, m1 = b1 & 7;
  float v0 = e0 ? __builtin_bit_cast(float, ((e0 + 120) << 23) | (m0 << 20))
              : (float)m0 * 0.001953125f;
  float v1 = e1 ? __builtin_bit_cast(float, ((e1 + 120) << 23) | (m1 << 20))
              : (float)m1 * 0.001953125f;
  r[0] = (b0 & 0x80) ? -v0 : v0;
  r[1] = (b1 & 0x80) ? -v1 : v1;
  return r;
#endif
}

__device__ __forceinline__ f32x2 fp8x2_lo(unsigned v) {
#if __has_builtin(__builtin_amdgcn_cvt_pk_f32_fp8)
  return __builtin_amdgcn_cvt_pk_f32_fp8((int)v, false);
#else
  return from_fp8x2((unsigned short)(v & 0xffffu));
#endif
}

__device__ __forceinline__ f32x2 fp8x2_hi(unsigned v) {
#if __has_builtin(__builtin_amdgcn_cvt_pk_f32_fp8)
  return __builtin_amdgcn_cvt_pk_f32_fp8((int)v, true);
#else
  return from_fp8x2((unsigned short)(v >> 16));
#endif
}

// ---------------- W pre-transpose: fp32 [k][COLS] -> bf16 [c][128] ----------------
// All 4 weight matrices in one launch; block ranges select the matrix.

__global__ __launch_bounds__(256) void k_wprep_all(
    const float* __restrict__ W1l, const float* __restrict__ W1r,
    const float* __restrict__ W2l, const float* __restrict__ W2r,
    __bf16* __restrict__ B1l, __bf16* __restrict__ B1r,
    __bf16* __restrict__ B2l, __bf16* __restrict__ B2r) {
  int b = blockIdx.x;
  const float* W;
  __bf16* Bt;
  int idx;
  bool wide;
  if (b < 64) {
    W = W1l; Bt = B1l; idx = b * 256 + threadIdx.x; wide = true;
  } else if (b < 128) {
    W = W1r; Bt = B1r; idx = (b - 64) * 256 + threadIdx.x; wide = true;
  } else if (b < 160) {
    W = W2l; Bt = B2l; idx = (b - 128) * 256 + threadIdx.x; wide = false;
  } else {
    W = W2r; Bt = B2r; idx = (b - 160) * 256 + threadIdx.x; wide = false;
  }
  int k = wide ? (idx >> 7) : (idx >> 6);
  int c = wide ? (idx & 127) : (idx & 63);
  Bt[c * K + k] = (__bf16)W[idx];  // small scattered 2B writes; L2-resident
}

// ---------------- bucketed CSR build ----------------

__global__ __launch_bounds__(256) void k_bhist(const int* __restrict__ dst,
                                               int* __restrict__ blockHist,
                                               int* __restrict__ bucketTotal,
                                               int E, int n, int nB) {
  extern __shared__ int hist[];
  for (int i = threadIdx.x; i < nB; i += 256) hist[i] = 0;
  __syncthreads();
  int base = blockIdx.x * EB, end = min(base + EB, E);
  for (int e = base + threadIdx.x; e < end; e += 256) {
    int d = dst[e];
    if ((unsigned)d < (unsigned)n) atomicAdd(&hist[d >> 8], 1);
  }
  __syncthreads();
  for (int i = threadIdx.x; i < nB; i += 256) {
    int v = hist[i];
    blockHist[(long)blockIdx.x * nB + i] = v;
    if (v) atomicAdd(&bucketTotal[i], v);
  }
}

__global__ __launch_bounds__(512) void k_btop(const int* __restrict__ bucketTotal,
                                              int* __restrict__ bucketBase,
                                              int* __restrict__ bucketCursor, int nB) {
  __shared__ int sh[512];
  int t = threadIdx.x;
  int s = (t < nB) ? bucketTotal[t] : 0;
  sh[t] = s;
  __syncthreads();
  for (int off = 1; off < 512; off <<= 1) {
    int v = (t >= off) ? sh[t - off] : 0;
    __syncthreads();
    sh[t] += v;
    __syncthreads();
  }
  if (t < nB) {
    int base = sh[t] - s;
    bucketBase[t] = base;
    bucketCursor[t] = base;
    if (t == nB - 1) bucketBase[nB] = sh[t];
  }
}

__global__ __launch_bounds__(256) void k_bscatter(const int* __restrict__ src,
                                                  const int* __restrict__ dst,
                                                  const int* __restrict__ blockHist,
                                                  int* __restrict__ bucketCursor,
                                                  unsigned* __restrict__ recs,
                                                  int E, int n, int nB) {
  extern __shared__ int cur[];
  for (int i = threadIdx.x; i < nB; i += 256) {
    int c = blockHist[(long)blockIdx.x * nB + i];
    cur[i] = c ? atomicAdd(&bucketCursor[i], c) : 0;
  }
  __syncthreads();
  int base = blockIdx.x * EB, end = min(base + EB, E);
  for (int e = base + threadIdx.x; e < end; e += 256) {
    int d = dst[e];
    if ((unsigned)d < (unsigned)n) {
      int s = min(max(src[e], 0), n - 1);
      int pos = atomicAdd(&cur[d >> 8], 1);
      recs[pos] = ((unsigned)s << 8) | (unsigned)(d & 255);
    }
  }
}

__global__ __launch_bounds__(256) void k_bfill(const unsigned* __restrict__ recs,
                                               const int* __restrict__ bucketBase,
                                               int* __restrict__ rowptr,
                                               int* __restrict__ col, int n, int nB) {
  __shared__ int degl[256];
  __shared__ int incl[256];
  int b = blockIdx.x, t = threadIdx.x;
  int rbeg = bucketBase[b], rend = bucketBase[b + 1];
  degl[t] = 0;
  __syncthreads();
  for (int i = rbeg + t; i < rend; i += 256)
    atomicAdd(&degl[recs[i] & 255], 1);
  __syncthreads();
  incl[t] = degl[t];
  __syncthreads();
  for (int off = 1; off < 256; off <<= 1) {
    int v = (t >= off) ? incl[t - off] : 0;
    __syncthreads();
    incl[t] += v;
    __syncthreads();
  }
  int excl = incl[t] - degl[t];
  int node = b * 256 + t;
  if (node <= n) rowptr[node] = rbeg + excl;
  __syncthreads();
  degl[t] = rbeg + excl;  // reuse as cursor
  __syncthreads();
  for (int i = rbeg + t; i < rend; i += 256) {
    unsigned r = recs[i];
    int pos = atomicAdd(&degl[r & 255], 1);
    col[pos] = (int)(r >> 8);
  }
}

// ---------------- bf16 MFMA GEMM (fused, wave-specialized panels) ----------------
// Block = 32 rows, 4 waves: waves 0-1 -> Wl panel (fp8 outA), waves 2-3 ->
// Wr panel (bf16 outB); each wave covers 32 rows x COLS/2 cols. ALL B
// fragments are preloaded into registers at kernel entry (16B/lane x 4kc x NI,
// issued before A staging -> latency hidden under stage + barrier drain).
// kc loop reads only LDS (A) + regs (B). A staged once per tile total.

template <int COLS, typename TIN>
__global__ __launch_bounds__(256, 4) void k_gemm_fused(const TIN* __restrict__ X,
                                                       const __bf16* __restrict__ Bta,
                                                       const __bf16* __restrict__ Btb,
                                                       unsigned char* __restrict__ outA,
                                                       __bf16* __restrict__ outB, int nrows) {
  constexpr int LD = 136;
  constexpr int NI = COLS / 32;  // 16-col fragments per wave (wave = COLS/2 wide)
  __shared__ __bf16 As[32 * LD];

  int tid = threadIdx.x;
  long row0 = (long)blockIdx.x * 32;

  int w = tid >> 6, lane = tid & 63;
  int m = lane & 15, quad = lane >> 4;
  int panel = w >> 1;
  int wcol = (w & 1) * (COLS / 2);
  const __bf16* Btg = panel ? Btb : Bta;

  // B fragments: register preload, issued FIRST (overlaps A staging below;
  // completed by the barrier's vmcnt drain). Static indexing -> registers.
  bf16x8 bq[4][NI];
#pragma unroll
  for (int kc = 0; kc < 4; ++kc)
#pragma unroll
    for (int ni = 0; ni < NI; ++ni)
      bq[kc][ni] = *(const bf16x8*)(Btg + (long)(wcol + ni * 16 + m) * K + kc * 32 + quad * 8);

  // stage A (convert to bf16 if fp32 input)
  if constexpr (std::is_same_v<TIN, float>) {
#pragma unroll
    for (int it = 0; it < 4; ++it) {
      int i = tid + it * 256;
      int r = i >> 5, c4 = (i & 31) << 2;
      long row = row0 + r;
      float4 v = make_float4(0.f, 0.f, 0.f, 0.f);
      if (row < nrows) v = *(const float4*)(X + row * K + c4);
      bf16x4 bb;
      bb[0] = (__bf16)v.x; bb[1] = (__bf16)v.y; bb[2] = (__bf16)v.z; bb[3] = (__bf16)v.w;
      *(bf16x4*)&As[r * LD + c4] = bb;
    }
  } else {
#pragma unroll
    for (int it = 0; it < 2; ++it) {
      int i = tid + it * 256;
      int r = i >> 4, c8 = (i & 15) << 3;
      long row = row0 + r;
      bf16x8 v = {};
      if (row < nrows) v = *(const bf16x8*)(X + row * K + c8);
      *(bf16x8*)&As[r * LD + c8] = v;
    }
  }
  __syncthreads();

  f32x4 acc[2][NI];
#pragma unroll
  for (int mi = 0; mi < 2; ++mi)
#pragma unroll
    for (int ni = 0; ni < NI; ++ni) acc[mi][ni] = (f32x4){0.f, 0.f, 0.f, 0.f};

#pragma unroll
  for (int kc = 0; kc < 4; ++kc) {
    int ko = kc * 32 + quad * 8;
    bf16x8 af[2];
#pragma unroll
    for (int mi = 0; mi < 2; ++mi)
      af[mi] = *(const bf16x8*)&As[(mi * 16 + m) * LD + ko];
#pragma unroll
    for (int mi = 0; mi < 2; ++mi)
#pragma unroll
      for (int ni = 0; ni < NI; ++ni)
        acc[mi][ni] = __builtin_amdgcn_mfma_f32_16x16x32_bf16(af[mi], bq[kc][ni], acc[mi][ni], 0, 0, 0);
  }

#pragma unroll
  for (int mi = 0; mi < 2; ++mi) {
#pragma unroll
    for (int r = 0; r < 4; ++r) {
      long grow = row0 + mi * 16 + quad * 4 + r;
      if (grow < nrows) {
#pragma unroll
        for (int ni = 0; ni < NI; ++ni) {
          long idx = grow * COLS + wcol + ni * 16 + m;
          float v = acc[mi][ni][r];
          if (panel == 0) outA[idx] = to_fp8(v);
          else            outB[idx] = (__bf16)v;
        }
      }
    }
  }
}

// ---------------- aggregation ----------------
// R10: quarter-per-node. Each 16-lane quarter owns one node; lane l owns
// channels [8l, 8l+8) for ALL edges of that node -> no cross-lane reduce,
// epilogue runs on all 64 lanes (4 nodes simultaneously). Edge indices
// preloaded 16-per-quarter with one coalesced wave load, broadcast
// per-edge via one ds_bpermute (__shfl from same-quarter lane; same exec
// group -> well-defined). 4 edges (one per quarter) per VMEM instruction.

template <bool RELU>
__global__ __launch_bounds__(256) void k_agg128(const unsigned char* __restrict__ Y,
                                                const __bf16* __restrict__ XR,
                                                const float* __restrict__ bias,
                                                const int* __restrict__ rowptr,
                                                const int* __restrict__ col,
                                                __bf16* __restrict__ out, int nnodes) {
  int wave = threadIdx.x >> 6, lane = threadIdx.x & 63;
  int quarter = lane >> 4, l = lane & 15;
  int sb = lane & 48;  // quarter * 16: bpermute source base
  int n = blockIdx.x * 16 + wave * 4 + quarter;
  bool valid = n < nnodes;
  int beg = 0, end = 0;
  if (valid) {
    beg = rowptr[n];
    end = rowptr[n + 1];
  }
  int co = l * 8;  // 8 fp8 channels per lane
  const unsigned char* Yc = Y + co;

  f32x2 av0 = {0.f, 0.f}, av1 = {0.f, 0.f}, av2 = {0.f, 0.f}, av3 = {0.f, 0.f};

  for (int base = beg; base < end; base += 16) {
    int cnt = min(end - base, 16);
    int idx = (l < cnt) ? col[base + l] : 0;  // one coalesced load / 16 edges
    int j = 0;
    for (; j + 3 < cnt; j += 4) {
      long s0 = (unsigned)__shfl(idx, sb + j);
      long s1 = (unsigned)__shfl(idx, sb + j + 1);
      long s2 = (unsigned)__shfl(idx, sb + j + 2);
      long s3 = (unsigned)__shfl(idx, sb + j + 3);
      uint2 v0 = *(const uint2*)(Yc + s0 * 128);
      uint2 v1 = *(const uint2*)(Yc + s1 * 128);
      uint2 v2 = *(const uint2*)(Yc + s2 * 128);
      uint2 v3 = *(const uint2*)(Yc + s3 * 128);
      av0 += fp8x2_lo(v0.x); av1 += fp8x2_hi(v0.x);
      av2 += fp8x2_lo(v0.y); av3 += fp8x2_hi(v0.y);
      av0 += fp8x2_lo(v1.x); av1 += fp8x2_hi(v1.x);
      av2 += fp8x2_lo(v1.y); av3 += fp8x2_hi(v1.y);
      av0 += fp8x2_lo(v2.x); av1 += fp8x2_hi(v2.x);
      av2 += fp8x2_lo(v2.y); av3 += fp8x2_hi(v2.y);
      av0 += fp8x2_lo(v3.x); av1 += fp8x2_hi(v3.x);
      av2 += fp8x2_lo(v3.y); av3 += fp8x2_hi(v3.y);
    }
    for (; j < cnt; ++j) {
      long s = (unsigned)__shfl(idx, sb + j);
      uint2 v = *(const uint2*)(Yc + s * 128);
      av0 += fp8x2_lo(v.x); av1 += fp8x2_hi(v.x);
      av2 += fp8x2_lo(v.y); av3 += fp8x2_hi(v.y);
    }
  }

  if (valid) {
    float inv = 1.f / (float)max(end - beg, 1);
    bf16x8 xv = *(const bf16x8*)(XR + (long)n * 128 + co);
    f32x4 b0 = *(const f32x4*)(bias + co);
    f32x4 b1 = *(const f32x4*)(bias + co + 4);
    float r0 = av0[0] * inv + (float)xv[0] + b0[0];
    float r1 = av0[1] * inv + (float)xv[1] + b0[1];
    float r2 = av1[0] * inv + (float)xv[2] + b0[2];
    float r3 = av1[1] * inv + (float)xv[3] + b0[3];
    float r4 = av2[0] * inv + (float)xv[4] + b1[0];
    float r5 = av2[1] * inv + (float)xv[5] + b1[1];
    float r6 = av3[0] * inv + (float)xv[6] + b1[2];
    float r7 = av3[1] * inv + (float)xv[7] + b1[3];
    if (RELU) {
      r0 = fmaxf(r0, 0.f); r1 = fmaxf(r1, 0.f);
      r2 = fmaxf(r2, 0.f); r3 = fmaxf(r3, 0.f);
      r4 = fmaxf(r4, 0.f); r5 = fmaxf(r5, 0.f);
      r6 = fmaxf(r6, 0.f); r7 = fmaxf(r7, 0.f);
    }
    bf16x8 o;
    o[0] = (__bf16)r0; o[1] = (__bf16)r1; o[2] = (__bf16)r2; o[3] = (__bf16)r3;
    o[4] = (__bf16)r4; o[5] = (__bf16)r5; o[6] = (__bf16)r6; o[7] = (__bf16)r7;
    *(bf16x8*)(out + (long)n * 128 + co) = o;
  }
}

__global__ __launch_bounds__(256) void k_agg64(const unsigned char* __restrict__ Y,
                                               const __bf16* __restrict__ XR,
                                               const float* __restrict__ bias,
                                               const int* __restrict__ rowptr,
                                               const int* __restrict__ col,
                                               float* __restrict__ out, int nnodes) {
  int wave = threadIdx.x >> 6, lane = threadIdx.x & 63;
  int quarter = lane >> 4, l = lane & 15;
  int sb = lane & 48;
  int n = blockIdx.x * 16 + wave * 4 + quarter;
  bool valid = n < nnodes;
  int beg = 0, end = 0;
  if (valid) {
    beg = rowptr[n];
    end = rowptr[n + 1];
  }
  int co = l * 4;  // 4 fp8 channels per lane
  const unsigned char* Yc = Y + co;

  f32x2 av0 = {0.f, 0.f}, av1 = {0.f, 0.f};

  for (int base = beg; base < end; base += 16) {
    int cnt = min(end - base, 16);
    int idx = (l < cnt) ? col[base + l] : 0;
    int j = 0;
    for (; j + 3 < cnt; j += 4) {
      long s0 = (unsigned)__shfl(idx, sb + j);
      long s1 = (unsigned)__shfl(idx, sb + j + 1);
      long s2 = (unsigned)__shfl(idx, sb + j + 2);
      long s3 = (unsigned)__shfl(idx, sb + j + 3);
      unsigned v0 = *(const unsigned*)(Yc + s0 * 64);
      unsigned v1 = *(const unsigned*)(Yc + s1 * 64);
      unsigned v2 = *(const unsigned*)(Yc + s2 * 64);
      unsigned v3 = *(const unsigned*)(Yc + s3 * 64);
      av0 += fp8x2_lo(v0); av1 += fp8x2_hi(v0);
      av0 += fp8x2_lo(v1); av1 += fp8x2_hi(v1);
      av0 += fp8x2_lo(v2); av1 += fp8x2_hi(v2);
      av0 += fp8x2_lo(v3); av1 += fp8x2_hi(v3);
    }
    for (; j < cnt; ++j) {
      long s = (unsigned)__shfl(idx, sb + j);
      unsigned v = *(const unsigned*)(Yc + s * 64);
      av0 += fp8x2_lo(v); av1 += fp8x2_hi(v);
    }
  }

  if (valid) {
    float inv = 1.f / (float)max(end - beg, 1);
    bf16x4 xv = *(const bf16x4*)(XR + (long)n * 64 + co);
    f32x4 bv = *(const f32x4*)(bias + co);
    f32x4 r;
    r[0] = av0[0] * inv + (float)xv[0] + bv[0];
    r[1] = av0[1] * inv + (float)xv[1] + bv[1];
    r[2] = av1[0] * inv + (float)xv[2] + bv[2];
    r[3] = av1[1] * inv + (float)xv[3] + bv[3];
    *(f32x4*)(out + (long)n * 64 + co) = r;
  }
}

// ---------------- launch ----------------

extern "C" void kernel_launch(void* const* d_in, const int* in_sizes, int n_in,
                              void* d_out, int out_size, void* d_ws, size_t ws_size,
                              hipStream_t stream) {
  const float* x   = (const float*)d_in[0];
  const int*   ei  = (const int*)d_in[1];
  const float* W1l = (const float*)d_in[2];
  const float* W1r = (const float*)d_in[3];
  const float* b1  = (const float*)d_in[4];
  const float* W2l = (const float*)d_in[5];
  const float* W2r = (const float*)d_in[6];
  const float* b2  = (const float*)d_in[7];
  float* out = (float*)d_out;

  int N = in_sizes[0] / K;   // 100000
  int E = in_sizes[1] / 2;   // 1600000
  const int* src = ei;
  const int* dst = ei + E;

  int nB = (N + 255) >> 8;          // 391 buckets
  int nblk = (E + EB - 1) / EB;     // 391 partition blocks

  char* ws = (char*)d_ws;
  size_t off = 0;
  auto alloc = [&](size_t bytes) {
    void* p = ws + off;
    off = (off + bytes + 255) & ~(size_t)255;
    return p;
  };
  int*      rowptr       = (int*)alloc(((size_t)N + 2) * 4);
  int*      col          = (int*)alloc((size_t)E * 4);
  int*      blockHist    = (int*)alloc((size_t)nblk * nB * 4);
  int*      bucketTotal  = (int*)alloc(((size_t)nB) * 4);
  int*      bucketBase   = (int*)alloc(((size_t)nB + 1) * 4);
  int*      bucketCursor = (int*)alloc((size_t)nB * 4);
  unsigned* recs         = (unsigned*)alloc((size_t)E * 4);
  unsigned char* y1      = (unsigned char*)alloc((size_t)N * 128);  // fp8
  __bf16*   xr           = (__bf16*)alloc((size_t)N * 128 * 2);
  __bf16*   h            = (__bf16*)alloc((size_t)N * 128 * 2);
  __bf16*   Bt1l         = (__bf16*)alloc((size_t)128 * K * 2);
  __bf16*   Bt1r         = (__bf16*)alloc((size_t)128 * K * 2);
  __bf16*   Bt2l         = (__bf16*)alloc((size_t)64 * K * 2);
  __bf16*   Bt2r         = (__bf16*)alloc((size_t)64 * K * 2);
  unsigned char* y2 = y1;  // layer-1 gather buffer dead after k_agg128; reuse
  __bf16*   hr = xr;

  // W pre-transpose: all 4 matrices, one launch (independent of CSR build)
  k_wprep_all<<<192, 256, 0, stream>>>(W1l, W1r, W2l, W2r, Bt1l, Bt1r, Bt2l, Bt2r);

  // CSR build (bucketed)
  hipMemsetAsync(bucketTotal, 0, (size_t)nB * 4, stream);
  k_bhist<<<nblk, 256, nB * 4, stream>>>(dst, blockHist, bucketTotal, E, N, nB);
  k_btop<<<1, 512, 0, stream>>>(bucketTotal, bucketBase, bucketCursor, nB);
  k_bscatter<<<nblk, 256, nB * 4, stream>>>(src, dst, blockHist, bucketCursor, recs, E, N, nB);
  k_bfill<<<nB, 256, 0, stream>>>(recs, bucketBase, rowptr, col, N, nB);

  int gx = (N + 31) / 32;
  // layer 1: y1 = fp8(x@W1l), xr = bf16(x@W1r); h = relu(mean(y1) + xr + b1)
  k_gemm_fused<128, float><<<gx, 256, 0, stream>>>(x, Bt1l, Bt1r, y1, xr, N);
  k_agg128<true><<<(N + 15) / 16, 256, 0, stream>>>(y1, xr, b1, rowptr, col, h, N);

  // layer 2: y2 = fp8(h@W2l), hr = bf16(h@W2r); out = mean(y2) + hr + b2
  k_gemm_fused<64, __bf16><<<gx, 256, 0, stream>>>(h, Bt2l, Bt2r, y2, hr, N);
  k_agg64<<<(N + 15) / 16, 256, 0, stream>>>(y2, hr, b2, rowptr, col, out, N);
}

// Round 5
// 268.331 us; speedup vs baseline: 1.0734x; 1.0629x over previous
//
#include <hip/hip_runtime.h>
#include <type_traits>

// GraphSAGE 2-layer, N=100k, C 128->128->64, E=1.6M, fp32 in/out.
// R8: pre-transposed bf16 W -> conflict-free GEMM B access.
// R9: latency-optimized aggregation (4 edges per VMEM instr).
// R10: quarter-per-node aggregation (no cross-lane reduce, full-wave epilogue).
// R11: fused-panel GEMM (A staged once for both Wl/Wr products).
// R12: wave-specialized panels + B reg-preload (FAILED: bq[4][4]=64 VGPR
//      didn't fit 128-cap -> compiler sank loads, VGPR_Count=48 proved it).
// R13: register math made to FIT — 512-thr blocks, 8 waves, wave = panel
//      (w>>2) x 32/16-col strip (w&3); bq[4][NI] = 32 VGPR (NI=COLS/64),
//      acc 32, af 16 -> ~105 total under __launch_bounds__(512,4)'s 128
//      cap. B preload survives; kc loop is pure LDS+reg; 2 blocks/CU.

constexpr int K = 128;
constexpr int EB = 4096;  // edges per partition block

typedef __bf16 bf16x2 __attribute__((ext_vector_type(2)));
typedef __bf16 bf16x4 __attribute__((ext_vector_type(4)));
typedef __bf16 bf16x8 __attribute__((ext_vector_type(8)));
typedef float f32x4 __attribute__((ext_vector_type(4)));
typedef float f32x2 __attribute__((ext_vector_type(2)));

// ---------------- fp8 e4m3 conversion ----------------

__device__ __forceinline__ unsigned char to_fp8(float v) {
#if __has_builtin(__builtin_amdgcn_cvt_pk_fp8_f32)
  int p = __builtin_amdgcn_cvt_pk_fp8_f32(v, v, 0, false);
  return (unsigned char)(p & 0xff);
#else
  unsigned u = __builtin_bit_cast(unsigned, v);
  unsigned s = (u >> 24) & 0x80u;
  float a = fabsf(v);
  if (a > 448.f) a = 448.f;
  unsigned bits;
  if (a < 0.015625f) {
    bits = (unsigned)(a * 512.f + 0.5f);
  } else {
    unsigned b = __builtin_bit_cast(unsigned, a);
    b += ((b >> 20) & 1) + 0x0007FFFF;
    unsigned e = (b >> 23) - 120;
    bits = (e << 3) | ((b >> 20) & 7);
    if (bits > 0x7E) bits = 0x7E;
  }
  return (unsigned char)(s | bits);
#endif
}

__device__ __forceinline__ f32x2 from_fp8x2(unsigned short u) {
#if __has_builtin(__builtin_amdgcn_cvt_pk_f32_fp8)
  return __builtin_amdgcn_cvt_pk_f32_fp8((int)u, false);
#else
  f32x2 r;
  unsigned b0 = u & 0xff, b1 = (u >> 8) & 0xff;
  unsigned e0 = (b0 >> 3) & 15, m0 = b0 & 7;
  unsigned e1 = (b1 >> 3) & 15, m1 = b1 & 7;
  float v0 = e0 ? __builtin_bit_cast(float, ((e0 + 120) << 23) | (m0 << 20))
              : (float)m0 * 0.001953125f;
  float v1 = e1 ? __builtin_bit_cast(float, ((e1 + 120) << 23) | (m1 << 20))
              : (float)m1 * 0.001953125f;
  r[0] = (b0 & 0x80) ? -v0 : v0;
  r[1] = (b1 & 0x80) ? -v1 : v1;
  return r;
#endif
}

__device__ __forceinline__ f32x2 fp8x2_lo(unsigned v) {
#if __has_builtin(__builtin_amdgcn_cvt_pk_f32_fp8)
  return __builtin_amdgcn_cvt_pk_f32_fp8((int)v, false);
#else
  return from_fp8x2((unsigned short)(v & 0xffffu));
#endif
}

__device__ __forceinline__ f32x2 fp8x2_hi(unsigned v) {
#if __has_builtin(__builtin_amdgcn_cvt_pk_f32_fp8)
  return __builtin_amdgcn_cvt_pk_f32_fp8((int)v, true);
#else
  return from_fp8x2((unsigned short)(v >> 16));
#endif
}

// ---------------- W pre-transpose: fp32 [k][COLS] -> bf16 [c][128] ----------------
// All 4 weight matrices in one launch; block ranges select the matrix.

__global__ __launch_bounds__(256) void k_wprep_all(
    const float* __restrict__ W1l, const float* __restrict__ W1r,
    const float* __restrict__ W2l, const float* __restrict__ W2r,
    __bf16* __restrict__ B1l, __bf16* __restrict__ B1r,
    __bf16* __restrict__ B2l, __bf16* __restrict__ B2r) {
  int b = blockIdx.x;
  const float* W;
  __bf16* Bt;
  int idx;
  bool wide;
  if (b < 64) {
    W = W1l; Bt = B1l; idx = b * 256 + threadIdx.x; wide = true;
  } else if (b < 128) {
    W = W1r; Bt = B1r; idx = (b - 64) * 256 + threadIdx.x; wide = true;
  } else if (b < 160) {
    W = W2l; Bt = B2l; idx = (b - 128) * 256 + threadIdx.x; wide = false;
  } else {
    W = W2r; Bt = B2r; idx = (b - 160) * 256 + threadIdx.x; wide = false;
  }
  int k = wide ? (idx >> 7) : (idx >> 6);
  int c = wide ? (idx & 127) : (idx & 63);
  Bt[c * K + k] = (__bf16)W[idx];  // small scattered 2B writes; L2-resident
}

// ---------------- bucketed CSR build ----------------

__global__ __launch_bounds__(256) void k_bhist(const int* __restrict__ dst,
                                               int* __restrict__ blockHist,
                                               int* __restrict__ bucketTotal,
                                               int E, int n, int nB) {
  extern __shared__ int hist[];
  for (int i = threadIdx.x; i < nB; i += 256) hist[i] = 0;
  __syncthreads();
  int base = blockIdx.x * EB, end = min(base + EB, E);
  for (int e = base + threadIdx.x; e < end; e += 256) {
    int d = dst[e];
    if ((unsigned)d < (unsigned)n) atomicAdd(&hist[d >> 8], 1);
  }
  __syncthreads();
  for (int i = threadIdx.x; i < nB; i += 256) {
    int v = hist[i];
    blockHist[(long)blockIdx.x * nB + i] = v;
    if (v) atomicAdd(&bucketTotal[i], v);
  }
}

__global__ __launch_bounds__(512) void k_btop(const int* __restrict__ bucketTotal,
                                              int* __restrict__ bucketBase,
                                              int* __restrict__ bucketCursor, int nB) {
  __shared__ int sh[512];
  int t = threadIdx.x;
  int s = (t < nB) ? bucketTotal[t] : 0;
  sh[t] = s;
  __syncthreads();
  for (int off = 1; off < 512; off <<= 1) {
    int v = (t >= off) ? sh[t - off] : 0;
    __syncthreads();
    sh[t] += v;
    __syncthreads();
  }
  if (t < nB) {
    int base = sh[t] - s;
    bucketBase[t] = base;
    bucketCursor[t] = base;
    if (t == nB - 1) bucketBase[nB] = sh[t];
  }
}

__global__ __launch_bounds__(256) void k_bscatter(const int* __restrict__ src,
                                                  const int* __restrict__ dst,
                                                  const int* __restrict__ blockHist,
                                                  int* __restrict__ bucketCursor,
                                                  unsigned* __restrict__ recs,
                                                  int E, int n, int nB) {
  extern __shared__ int cur[];
  for (int i = threadIdx.x; i < nB; i += 256) {
    int c = blockHist[(long)blockIdx.x * nB + i];
    cur[i] = c ? atomicAdd(&bucketCursor[i], c) : 0;
  }
  __syncthreads();
  int base = blockIdx.x * EB, end = min(base + EB, E);
  for (int e = base + threadIdx.x; e < end; e += 256) {
    int d = dst[e];
    if ((unsigned)d < (unsigned)n) {
      int s = min(max(src[e], 0), n - 1);
      int pos = atomicAdd(&cur[d >> 8], 1);
      recs[pos] = ((unsigned)s << 8) | (unsigned)(d & 255);
    }
  }
}

__global__ __launch_bounds__(256) void k_bfill(const unsigned* __restrict__ recs,
                                               const int* __restrict__ bucketBase,
                                               int* __restrict__ rowptr,
                                               int* __restrict__ col, int n, int nB) {
  __shared__ int degl[256];
  __shared__ int incl[256];
  int b = blockIdx.x, t = threadIdx.x;
  int rbeg = bucketBase[b], rend = bucketBase[b + 1];
  degl[t] = 0;
  __syncthreads();
  for (int i = rbeg + t; i < rend; i += 256)
    atomicAdd(&degl[recs[i] & 255], 1);
  __syncthreads();
  incl[t] = degl[t];
  __syncthreads();
  for (int off = 1; off < 256; off <<= 1) {
    int v = (t >= off) ? incl[t - off] : 0;
    __syncthreads();
    incl[t] += v;
    __syncthreads();
  }
  int excl = incl[t] - degl[t];
  int node = b * 256 + t;
  if (node <= n) rowptr[node] = rbeg + excl;
  __syncthreads();
  degl[t] = rbeg + excl;  // reuse as cursor
  __syncthreads();
  for (int i = rbeg + t; i < rend; i += 256) {
    unsigned r = recs[i];
    int pos = atomicAdd(&degl[r & 255], 1);
    col[pos] = (int)(r >> 8);
  }
}

// ---------------- bf16 MFMA GEMM (fused, wave-specialized, reg-B) ----------------
// Block = 64 rows, 512 threads (8 waves). Wave w: panel = w>>2 (Wl->fp8 /
// Wr->bf16), col strip (w&3)*16*NI, NI = COLS/64. Per wave: 64 rows x
// 16*NI cols -> acc[4][NI] (32 VGPR at NI=2), bq[4][NI] B fragments
// (32 VGPR) preloaded BEFORE A staging (latency hidden under stage +
// barrier); af[4] (16 VGPR). Total ~105 VGPR < 128 cap of (512,4) -> B
// stays register-resident (R12's failure mode: 64-VGPR bq got sunk).
// kc loop touches only LDS(A) + regs(B). A staged once per tile.

template <int COLS, typename TIN>
__global__ __launch_bounds__(512, 4) void k_gemm_fused(const TIN* __restrict__ X,
                                                       const __bf16* __restrict__ Bta,
                                                       const __bf16* __restrict__ Btb,
                                                       unsigned char* __restrict__ outA,
                                                       __bf16* __restrict__ outB, int nrows) {
  constexpr int LD = 136;
  constexpr int NI = COLS / 64;  // 16-col fragments per wave
  __shared__ __bf16 As[64 * LD];

  int tid = threadIdx.x;
  long row0 = (long)blockIdx.x * 64;

  int w = tid >> 6, lane = tid & 63;
  int m = lane & 15, quad = lane >> 4;
  int panel = w >> 2;
  int wcol = (w & 3) * (16 * NI);
  const __bf16* Btg = panel ? Btb : Bta;

  // B fragments: register preload, issued FIRST (overlaps A staging below;
  // completed by the barrier's vmcnt drain). Static indexing -> registers.
  bf16x8 bq[4][NI];
#pragma unroll
  for (int kc = 0; kc < 4; ++kc)
#pragma unroll
    for (int ni = 0; ni < NI; ++ni)
      bq[kc][ni] = *(const bf16x8*)(Btg + (long)(wcol + ni * 16 + m) * K + kc * 32 + quad * 8);

  // stage A (convert to bf16 if fp32 input): 64 rows x 128 cols
  if constexpr (std::is_same_v<TIN, float>) {
#pragma unroll
    for (int it = 0; it < 4; ++it) {
      int i = tid + it * 512;
      int r = i >> 5, c4 = (i & 31) << 2;
      long row = row0 + r;
      float4 v = make_float4(0.f, 0.f, 0.f, 0.f);
      if (row < nrows) v = *(const float4*)(X + row * K + c4);
      bf16x4 bb;
      bb[0] = (__bf16)v.x; bb[1] = (__bf16)v.y; bb[2] = (__bf16)v.z; bb[3] = (__bf16)v.w;
      *(bf16x4*)&As[r * LD + c4] = bb;
    }
  } else {
#pragma unroll
    for (int it = 0; it < 2; ++it) {
      int i = tid + it * 512;
      int r = i >> 4, c8 = (i & 15) << 3;
      long row = row0 + r;
      bf16x8 v = {};
      if (row < nrows) v = *(const bf16x8*)(X + row * K + c8);
      *(bf16x8*)&As[r * LD + c8] = v;
    }
  }
  __syncthreads();

  f32x4 acc[4][NI];
#pragma unroll
  for (int mi = 0; mi < 4; ++mi)
#pragma unroll
    for (int ni = 0; ni < NI; ++ni) acc[mi][ni] = (f32x4){0.f, 0.f, 0.f, 0.f};

#pragma unroll
  for (int kc = 0; kc < 4; ++kc) {
    int ko = kc * 32 + quad * 8;
    bf16x8 af[4];
#pragma unroll
    for (int mi = 0; mi < 4; ++mi)
      af[mi] = *(const bf16x8*)&As[(mi * 16 + m) * LD + ko];
#pragma unroll
    for (int mi = 0; mi < 4; ++mi)
#pragma unroll
      for (int ni = 0; ni < NI; ++ni)
        acc[mi][ni] = __builtin_amdgcn_mfma_f32_16x16x32_bf16(af[mi], bq[kc][ni], acc[mi][ni], 0, 0, 0);
  }

#pragma unroll
  for (int mi = 0; mi < 4; ++mi) {
#pragma unroll
    for (int r = 0; r < 4; ++r) {
      long grow = row0 + mi * 16 + quad * 4 + r;
      if (grow < nrows) {
#pragma unroll
        for (int ni = 0; ni < NI; ++ni) {
          long idx = grow * COLS + wcol + ni * 16 + m;
          float v = acc[mi][ni][r];
          if (panel == 0) outA[idx] = to_fp8(v);
          else            outB[idx] = (__bf16)v;
        }
      }
    }
  }
}

// ---------------- aggregation ----------------
// R10: quarter-per-node. Each 16-lane quarter owns one node; lane l owns
// channels [8l, 8l+8) for ALL edges of that node -> no cross-lane reduce,
// epilogue runs on all 64 lanes (4 nodes simultaneously). Edge indices
// preloaded 16-per-quarter with one coalesced wave load, broadcast
// per-edge via one ds_bpermute (__shfl from same-quarter lane; same exec
// group -> well-defined). 4 edges (one per quarter) per VMEM instruction.

template <bool RELU>
__global__ __launch_bounds__(256) void k_agg128(const unsigned char* __restrict__ Y,
                                                const __bf16* __restrict__ XR,
                                                const float* __restrict__ bias,
                                                const int* __restrict__ rowptr,
                                                const int* __restrict__ col,
                                                __bf16* __restrict__ out, int nnodes) {
  int wave = threadIdx.x >> 6, lane = threadIdx.x & 63;
  int quarter = lane >> 4, l = lane & 15;
  int sb = lane & 48;  // quarter * 16: bpermute source base
  int n = blockIdx.x * 16 + wave * 4 + quarter;
  bool valid = n < nnodes;
  int beg = 0, end = 0;
  if (valid) {
    beg = rowptr[n];
    end = rowptr[n + 1];
  }
  int co = l * 8;  // 8 fp8 channels per lane
  const unsigned char* Yc = Y + co;

  f32x2 av0 = {0.f, 0.f}, av1 = {0.f, 0.f}, av2 = {0.f, 0.f}, av3 = {0.f, 0.f};

  for (int base = beg; base < end; base += 16) {
    int cnt = min(end - base, 16);
    int idx = (l < cnt) ? col[base + l] : 0;  // one coalesced load / 16 edges
    int j = 0;
    for (; j + 3 < cnt; j += 4) {
      long s0 = (unsigned)__shfl(idx, sb + j);
      long s1 = (unsigned)__shfl(idx, sb + j + 1);
      long s2 = (unsigned)__shfl(idx, sb + j + 2);
      long s3 = (unsigned)__shfl(idx, sb + j + 3);
      uint2 v0 = *(const uint2*)(Yc + s0 * 128);
      uint2 v1 = *(const uint2*)(Yc + s1 * 128);
      uint2 v2 = *(const uint2*)(Yc + s2 * 128);
      uint2 v3 = *(const uint2*)(Yc + s3 * 128);
      av0 += fp8x2_lo(v0.x); av1 += fp8x2_hi(v0.x);
      av2 += fp8x2_lo(v0.y); av3 += fp8x2_hi(v0.y);
      av0 += fp8x2_lo(v1.x); av1 += fp8x2_hi(v1.x);
      av2 += fp8x2_lo(v1.y); av3 += fp8x2_hi(v1.y);
      av0 += fp8x2_lo(v2.x); av1 += fp8x2_hi(v2.x);
      av2 += fp8x2_lo(v2.y); av3 += fp8x2_hi(v2.y);
      av0 += fp8x2_lo(v3.x); av1 += fp8x2_hi(v3.x);
      av2 += fp8x2_lo(v3.y); av3 += fp8x2_hi(v3.y);
    }
    for (; j < cnt; ++j) {
      long s = (unsigned)__shfl(idx, sb + j);
      uint2 v = *(const uint2*)(Yc + s * 128);
      av0 += fp8x2_lo(v.x); av1 += fp8x2_hi(v.x);
      av2 += fp8x2_lo(v.y); av3 += fp8x2_hi(v.y);
    }
  }

  if (valid) {
    float inv = 1.f / (float)max(end - beg, 1);
    bf16x8 xv = *(const bf16x8*)(XR + (long)n * 128 + co);
    f32x4 b0 = *(const f32x4*)(bias + co);
    f32x4 b1 = *(const f32x4*)(bias + co + 4);
    float r0 = av0[0] * inv + (float)xv[0] + b0[0];
    float r1 = av0[1] * inv + (float)xv[1] + b0[1];
    float r2 = av1[0] * inv + (float)xv[2] + b0[2];
    float r3 = av1[1] * inv + (float)xv[3] + b0[3];
    float r4 = av2[0] * inv + (float)xv[4] + b1[0];
    float r5 = av2[1] * inv + (float)xv[5] + b1[1];
    float r6 = av3[0] * inv + (float)xv[6] + b1[2];
    float r7 = av3[1] * inv + (float)xv[7] + b1[3];
    if (RELU) {
      r0 = fmaxf(r0, 0.f); r1 = fmaxf(r1, 0.f);
      r2 = fmaxf(r2, 0.f); r3 = fmaxf(r3, 0.f);
      r4 = fmaxf(r4, 0.f); r5 = fmaxf(r5, 0.f);
      r6 = fmaxf(r6, 0.f); r7 = fmaxf(r7, 0.f);
    }
    bf16x8 o;
    o[0] = (__bf16)r0; o[1] = (__bf16)r1; o[2] = (__bf16)r2; o[3] = (__bf16)r3;
    o[4] = (__bf16)r4; o[5] = (__bf16)r5; o[6] = (__bf16)r6; o[7] = (__bf16)r7;
    *(bf16x8*)(out + (long)n * 128 + co) = o;
  }
}

__global__ __launch_bounds__(256) void k_agg64(const unsigned char* __restrict__ Y,
                                               const __bf16* __restrict__ XR,
                                               const float* __restrict__ bias,
                                               const int* __restrict__ rowptr,
                                               const int* __restrict__ col,
                                               float* __restrict__ out, int nnodes) {
  int wave = threadIdx.x >> 6, lane = threadIdx.x & 63;
  int quarter = lane >> 4, l = lane & 15;
  int sb = lane & 48;
  int n = blockIdx.x * 16 + wave * 4 + quarter;
  bool valid = n < nnodes;
  int beg = 0, end = 0;
  if (valid) {
    beg = rowptr[n];
    end = rowptr[n + 1];
  }
  int co = l * 4;  // 4 fp8 channels per lane
  const unsigned char* Yc = Y + co;

  f32x2 av0 = {0.f, 0.f}, av1 = {0.f, 0.f};

  for (int base = beg; base < end; base += 16) {
    int cnt = min(end - base, 16);
    int idx = (l < cnt) ? col[base + l] : 0;
    int j = 0;
    for (; j + 3 < cnt; j += 4) {
      long s0 = (unsigned)__shfl(idx, sb + j);
      long s1 = (unsigned)__shfl(idx, sb + j + 1);
      long s2 = (unsigned)__shfl(idx, sb + j + 2);
      long s3 = (unsigned)__shfl(idx, sb + j + 3);
      unsigned v0 = *(const unsigned*)(Yc + s0 * 64);
      unsigned v1 = *(const unsigned*)(Yc + s1 * 64);
      unsigned v2 = *(const unsigned*)(Yc + s2 * 64);
      unsigned v3 = *(const unsigned*)(Yc + s3 * 64);
      av0 += fp8x2_lo(v0); av1 += fp8x2_hi(v0);
      av0 += fp8x2_lo(v1); av1 += fp8x2_hi(v1);
      av0 += fp8x2_lo(v2); av1 += fp8x2_hi(v2);
      av0 += fp8x2_lo(v3); av1 += fp8x2_hi(v3);
    }
    for (; j < cnt; ++j) {
      long s = (unsigned)__shfl(idx, sb + j);
      unsigned v = *(const unsigned*)(Yc + s * 64);
      av0 += fp8x2_lo(v); av1 += fp8x2_hi(v);
    }
  }

  if (valid) {
    float inv = 1.f / (float)max(end - beg, 1);
    bf16x4 xv = *(const bf16x4*)(XR + (long)n * 64 + co);
    f32x4 bv = *(const f32x4*)(bias + co);
    f32x4 r;
    r[0] = av0[0] * inv + (float)xv[0] + bv[0];
    r[1] = av0[1] * inv + (float)xv[1] + bv[1];
    r[2] = av1[0] * inv + (float)xv[2] + bv[2];
    r[3] = av1[1] * inv + (float)xv[3] + bv[3];
    *(f32x4*)(out + (long)n * 64 + co) = r;
  }
}

// ---------------- launch ----------------

extern "C" void kernel_launch(void* const* d_in, const int* in_sizes, int n_in,
                              void* d_out, int out_size, void* d_ws, size_t ws_size,
                              hipStream_t stream) {
  const float* x   = (const float*)d_in[0];
  const int*   ei  = (const int*)d_in[1];
  const float* W1l = (const float*)d_in[2];
  const float* W1r = (const float*)d_in[3];
  const float* b1  = (const float*)d_in[4];
  const float* W2l = (const float*)d_in[5];
  const float* W2r = (const float*)d_in[6];
  const float* b2  = (const float*)d_in[7];
  float* out = (float*)d_out;

  int N = in_sizes[0] / K;   // 100000
  int E = in_sizes[1] / 2;   // 1600000
  const int* src = ei;
  const int* dst = ei + E;

  int nB = (N + 255) >> 8;          // 391 buckets
  int nblk = (E + EB - 1) / EB;     // 391 partition blocks

  char* ws = (char*)d_ws;
  size_t off = 0;
  auto alloc = [&](size_t bytes) {
    void* p = ws + off;
    off = (off + bytes + 255) & ~(size_t)255;
    return p;
  };
  int*      rowptr       = (int*)alloc(((size_t)N + 2) * 4);
  int*      col          = (int*)alloc((size_t)E * 4);
  int*      blockHist    = (int*)alloc((size_t)nblk * nB * 4);
  int*      bucketTotal  = (int*)alloc(((size_t)nB) * 4);
  int*      bucketBase   = (int*)alloc(((size_t)nB + 1) * 4);
  int*      bucketCursor = (int*)alloc((size_t)nB * 4);
  unsigned* recs         = (unsigned*)alloc((size_t)E * 4);
  unsigned char* y1      = (unsigned char*)alloc((size_t)N * 128);  // fp8
  __bf16*   xr           = (__bf16*)alloc((size_t)N * 128 * 2);
  __bf16*   h            = (__bf16*)alloc((size_t)N * 128 * 2);
  __bf16*   Bt1l         = (__bf16*)alloc((size_t)128 * K * 2);
  __bf16*   Bt1r         = (__bf16*)alloc((size_t)128 * K * 2);
  __bf16*   Bt2l         = (__bf16*)alloc((size_t)64 * K * 2);
  __bf16*   Bt2r         = (__bf16*)alloc((size_t)64 * K * 2);
  unsigned char* y2 = y1;  // layer-1 gather buffer dead after k_agg128; reuse
  __bf16*   hr = xr;

  // W pre-transpose: all 4 matrices, one launch (independent of CSR build)
  k_wprep_all<<<192, 256, 0, stream>>>(W1l, W1r, W2l, W2r, Bt1l, Bt1r, Bt2l, Bt2r);

  // CSR build (bucketed)
  hipMemsetAsync(bucketTotal, 0, (size_t)nB * 4, stream);
  k_bhist<<<nblk, 256, nB * 4, stream>>>(dst, blockHist, bucketTotal, E, N, nB);
  k_btop<<<1, 512, 0, stream>>>(bucketTotal, bucketBase, bucketCursor, nB);
  k_bscatter<<<nblk, 256, nB * 4, stream>>>(src, dst, blockHist, bucketCursor, recs, E, N, nB);
  k_bfill<<<nB, 256, 0, stream>>>(recs, bucketBase, rowptr, col, N, nB);

  int gx = (N + 63) / 64;
  // layer 1: y1 = fp8(x@W1l), xr = bf16(x@W1r); h = relu(mean(y1) + xr + b1)
  k_gemm_fused<128, float><<<gx, 512, 0, stream>>>(x, Bt1l, Bt1r, y1, xr, N);
  k_agg128<true><<<(N + 15) / 16, 256, 0, stream>>>(y1, xr, b1, rowptr, col, h, N);

  // layer 2: y2 = fp8(h@W2l), hr = bf16(h@W2r); out = mean(y2) + hr + b2
  k_gemm_fused<64, __bf16><<<gx, 512, 0, stream>>>(h, Bt2l, Bt2r, y2, hr, N);
  k_agg64<<<(N + 15) / 16, 256, 0, stream>>>(y2, hr, b2, rowptr, col, out, N);
}

// Round 6
// 265.953 us; speedup vs baseline: 1.0830x; 1.0089x over previous
//
#include <hip/hip_runtime.h>
#include <type_traits>

// GraphSAGE 2-layer, N=100k, C 128->128->64, E=1.6M, fp32 in/out.
// R8: pre-transposed bf16 W -> conflict-free GEMM B access.
// R9: latency-optimized aggregation (4 edges per VMEM instr).
// R10: quarter-per-node aggregation (no cross-lane reduce, full-wave epilogue).
// R11: fused-panel GEMM (A staged once for both Wl/Wr products).
// R12: wave-specialized panels + B reg-preload (FAILED: 64-VGPR bq sunk).
// R13: halved per-wave B footprint (FAILED AGAIN: VGPR_Count=40 -> compiler
//      sank the loads past the barrier into the kc loop; legal sink-to-
//      reduce-pressure scheduling).
// R14: FORCE residency — asm volatile("" :: "v"(bq)) keep-alive pins after
//      staging, before __syncthreads(): loads must complete into registers
//      by the barrier and cannot be re-sunk. kc loop = pure LDS+reg.

constexpr int K = 128;
constexpr int EB = 4096;  // edges per partition block

typedef __bf16 bf16x2 __attribute__((ext_vector_type(2)));
typedef __bf16 bf16x4 __attribute__((ext_vector_type(4)));
typedef __bf16 bf16x8 __attribute__((ext_vector_type(8)));
typedef float f32x4 __attribute__((ext_vector_type(4)));
typedef float f32x2 __attribute__((ext_vector_type(2)));

// ---------------- fp8 e4m3 conversion ----------------

__device__ __forceinline__ unsigned char to_fp8(float v) {
#if __has_builtin(__builtin_amdgcn_cvt_pk_fp8_f32)
  int p = __builtin_amdgcn_cvt_pk_fp8_f32(v, v, 0, false);
  return (unsigned char)(p & 0xff);
#else
  unsigned u = __builtin_bit_cast(unsigned, v);
  unsigned s = (u >> 24) & 0x80u;
  float a = fabsf(v);
  if (a > 448.f) a = 448.f;
  unsigned bits;
  if (a < 0.015625f) {
    bits = (unsigned)(a * 512.f + 0.5f);
  } else {
    unsigned b = __builtin_bit_cast(unsigned, a);
    b += ((b >> 20) & 1) + 0x0007FFFF;
    unsigned e = (b >> 23) - 120;
    bits = (e << 3) | ((b >> 20) & 7);
    if (bits > 0x7E) bits = 0x7E;
  }
  return (unsigned char)(s | bits);
#endif
}

__device__ __forceinline__ f32x2 from_fp8x2(unsigned short u) {
#if __has_builtin(__builtin_amdgcn_cvt_pk_f32_fp8)
  return __builtin_amdgcn_cvt_pk_f32_fp8((int)u, false);
#else
  f32x2 r;
  unsigned b0 = u & 0xff, b1 = (u >> 8) & 0xff;
  unsigned e0 = (b0 >> 3) & 15, m0 = b0 & 7;
  unsigned e1 = (b1 >> 3) & 15, m1 = b1 & 7;
  float v0 = e0 ? __builtin_bit_cast(float, ((e0 + 120) << 23) | (m0 << 20))
              : (float)m0 * 0.001953125f;
  float v1 = e1 ? __builtin_bit_cast(float, ((e1 + 120) << 23) | (m1 << 20))
              : (float)m1 * 0.001953125f;
  r[0] = (b0 & 0x80) ? -v0 : v0;
  r[1] = (b1 & 0x80) ? -v1 : v1;
  return r;
#endif
}

__device__ __forceinline__ f32x2 fp8x2_lo(unsigned v) {
#if __has_builtin(__builtin_amdgcn_cvt_pk_f32_fp8)
  return __builtin_amdgcn_cvt_pk_f32_fp8((int)v, false);
#else
  return from_fp8x2((unsigned short)(v & 0xffffu));
#endif
}

__device__ __forceinline__ f32x2 fp8x2_hi(unsigned v) {
#if __has_builtin(__builtin_amdgcn_cvt_pk_f32_fp8)
  return __builtin_amdgcn_cvt_pk_f32_fp8((int)v, true);
#else
  return from_fp8x2((unsigned short)(v >> 16));
#endif
}

// ---------------- W pre-transpose: fp32 [k][COLS] -> bf16 [c][128] ----------------
// All 4 weight matrices in one launch; block ranges select the matrix.

__global__ __launch_bounds__(256) void k_wprep_all(
    const float* __restrict__ W1l, const float* __restrict__ W1r,
    const float* __restrict__ W2l, const float* __restrict__ W2r,
    __bf16* __restrict__ B1l, __bf16* __restrict__ B1r,
    __bf16* __restrict__ B2l, __bf16* __restrict__ B2r) {
  int b = blockIdx.x;
  const float* W;
  __bf16* Bt;
  int idx;
  bool wide;
  if (b < 64) {
    W = W1l; Bt = B1l; idx = b * 256 + threadIdx.x; wide = true;
  } else if (b < 128) {
    W = W1r; Bt = B1r; idx = (b - 64) * 256 + threadIdx.x; wide = true;
  } else if (b < 160) {
    W = W2l; Bt = B2l; idx = (b - 128) * 256 + threadIdx.x; wide = false;
  } else {
    W = W2r; Bt = B2r; idx = (b - 160) * 256 + threadIdx.x; wide = false;
  }
  int k = wide ? (idx >> 7) : (idx >> 6);
  int c = wide ? (idx & 127) : (idx & 63);
  Bt[c * K + k] = (__bf16)W[idx];  // small scattered 2B writes; L2-resident
}

// ---------------- bucketed CSR build ----------------

__global__ __launch_bounds__(256) void k_bhist(const int* __restrict__ dst,
                                               int* __restrict__ blockHist,
                                               int* __restrict__ bucketTotal,
                                               int E, int n, int nB) {
  extern __shared__ int hist[];
  for (int i = threadIdx.x; i < nB; i += 256) hist[i] = 0;
  __syncthreads();
  int base = blockIdx.x * EB, end = min(base + EB, E);
  for (int e = base + threadIdx.x; e < end; e += 256) {
    int d = dst[e];
    if ((unsigned)d < (unsigned)n) atomicAdd(&hist[d >> 8], 1);
  }
  __syncthreads();
  for (int i = threadIdx.x; i < nB; i += 256) {
    int v = hist[i];
    blockHist[(long)blockIdx.x * nB + i] = v;
    if (v) atomicAdd(&bucketTotal[i], v);
  }
}

__global__ __launch_bounds__(512) void k_btop(const int* __restrict__ bucketTotal,
                                              int* __restrict__ bucketBase,
                                              int* __restrict__ bucketCursor, int nB) {
  __shared__ int sh[512];
  int t = threadIdx.x;
  int s = (t < nB) ? bucketTotal[t] : 0;
  sh[t] = s;
  __syncthreads();
  for (int off = 1; off < 512; off <<= 1) {
    int v = (t >= off) ? sh[t - off] : 0;
    __syncthreads();
    sh[t] += v;
    __syncthreads();
  }
  if (t < nB) {
    int base = sh[t] - s;
    bucketBase[t] = base;
    bucketCursor[t] = base;
    if (t == nB - 1) bucketBase[nB] = sh[t];
  }
}

__global__ __launch_bounds__(256) void k_bscatter(const int* __restrict__ src,
                                                  const int* __restrict__ dst,
                                                  const int* __restrict__ blockHist,
                                                  int* __restrict__ bucketCursor,
                                                  unsigned* __restrict__ recs,
                                                  int E, int n, int nB) {
  extern __shared__ int cur[];
  for (int i = threadIdx.x; i < nB; i += 256) {
    int c = blockHist[(long)blockIdx.x * nB + i];
    cur[i] = c ? atomicAdd(&bucketCursor[i], c) : 0;
  }
  __syncthreads();
  int base = blockIdx.x * EB, end = min(base + EB, E);
  for (int e = base + threadIdx.x; e < end; e += 256) {
    int d = dst[e];
    if ((unsigned)d < (unsigned)n) {
      int s = min(max(src[e], 0), n - 1);
      int pos = atomicAdd(&cur[d >> 8], 1);
      recs[pos] = ((unsigned)s << 8) | (unsigned)(d & 255);
    }
  }
}

__global__ __launch_bounds__(256) void k_bfill(const unsigned* __restrict__ recs,
                                               const int* __restrict__ bucketBase,
                                               int* __restrict__ rowptr,
                                               int* __restrict__ col, int n, int nB) {
  __shared__ int degl[256];
  __shared__ int incl[256];
  int b = blockIdx.x, t = threadIdx.x;
  int rbeg = bucketBase[b], rend = bucketBase[b + 1];
  degl[t] = 0;
  __syncthreads();
  for (int i = rbeg + t; i < rend; i += 256)
    atomicAdd(&degl[recs[i] & 255], 1);
  __syncthreads();
  incl[t] = degl[t];
  __syncthreads();
  for (int off = 1; off < 256; off <<= 1) {
    int v = (t >= off) ? incl[t - off] : 0;
    __syncthreads();
    incl[t] += v;
    __syncthreads();
  }
  int excl = incl[t] - degl[t];
  int node = b * 256 + t;
  if (node <= n) rowptr[node] = rbeg + excl;
  __syncthreads();
  degl[t] = rbeg + excl;  // reuse as cursor
  __syncthreads();
  for (int i = rbeg + t; i < rend; i += 256) {
    unsigned r = recs[i];
    int pos = atomicAdd(&degl[r & 255], 1);
    col[pos] = (int)(r >> 8);
  }
}

// ---------------- bf16 MFMA GEMM (fused, wave-specialized, pinned reg-B) ---------
// Block = 64 rows, 512 threads (8 waves). Wave w: panel = w>>2 (Wl->fp8 /
// Wr->bf16), col strip (w&3)*16*NI, NI = COLS/64. bq[4][NI] B fragments
// issued first, then PINNED into registers via asm keep-alive uses placed
// before __syncthreads() — prevents the R12/R13 failure where the
// scheduler sank the loads into the kc loop (serial L2 round trips).
// kc loop touches only LDS(A) + regs(B). A staged once per tile.

template <int COLS, typename TIN>
__global__ __launch_bounds__(512, 4) void k_gemm_fused(const TIN* __restrict__ X,
                                                       const __bf16* __restrict__ Bta,
                                                       const __bf16* __restrict__ Btb,
                                                       unsigned char* __restrict__ outA,
                                                       __bf16* __restrict__ outB, int nrows) {
  constexpr int LD = 136;
  constexpr int NI = COLS / 64;  // 16-col fragments per wave
  __shared__ __bf16 As[64 * LD];

  int tid = threadIdx.x;
  long row0 = (long)blockIdx.x * 64;

  int w = tid >> 6, lane = tid & 63;
  int m = lane & 15, quad = lane >> 4;
  int panel = w >> 2;
  int wcol = (w & 3) * (16 * NI);
  const __bf16* Btg = panel ? Btb : Bta;

  // B fragments: issue loads FIRST (overlap A staging below).
  bf16x8 bq[4][NI];
#pragma unroll
  for (int kc = 0; kc < 4; ++kc)
#pragma unroll
    for (int ni = 0; ni < NI; ++ni)
      bq[kc][ni] = *(const bf16x8*)(Btg + (long)(wcol + ni * 16 + m) * K + kc * 32 + quad * 8);

  // stage A (convert to bf16 if fp32 input): 64 rows x 128 cols
  if constexpr (std::is_same_v<TIN, float>) {
#pragma unroll
    for (int it = 0; it < 4; ++it) {
      int i = tid + it * 512;
      int r = i >> 5, c4 = (i & 31) << 2;
      long row = row0 + r;
      float4 v = make_float4(0.f, 0.f, 0.f, 0.f);
      if (row < nrows) v = *(const float4*)(X + row * K + c4);
      bf16x4 bb;
      bb[0] = (__bf16)v.x; bb[1] = (__bf16)v.y; bb[2] = (__bf16)v.z; bb[3] = (__bf16)v.w;
      *(bf16x4*)&As[r * LD + c4] = bb;
    }
  } else {
#pragma unroll
    for (int it = 0; it < 2; ++it) {
      int i = tid + it * 512;
      int r = i >> 4, c8 = (i & 15) << 3;
      long row = row0 + r;
      bf16x8 v = {};
      if (row < nrows) v = *(const bf16x8*)(X + row * K + c8);
      *(bf16x8*)&As[r * LD + c8] = v;
    }
  }

  // PIN: hard use-point for every bq fragment BEFORE the barrier. Loads
  // must complete into registers here; scheduler cannot sink them into
  // the kc loop (R12/R13 failure mode). The vmcnt drain overlaps the
  // barrier's own drain of the A-staging stores.
#pragma unroll
  for (int kc = 0; kc < 4; ++kc)
#pragma unroll
    for (int ni = 0; ni < NI; ++ni)
      asm volatile("" :: "v"(bq[kc][ni]));

  __syncthreads();

  f32x4 acc[4][NI];
#pragma unroll
  for (int mi = 0; mi < 4; ++mi)
#pragma unroll
    for (int ni = 0; ni < NI; ++ni) acc[mi][ni] = (f32x4){0.f, 0.f, 0.f, 0.f};

#pragma unroll
  for (int kc = 0; kc < 4; ++kc) {
    int ko = kc * 32 + quad * 8;
    bf16x8 af[4];
#pragma unroll
    for (int mi = 0; mi < 4; ++mi)
      af[mi] = *(const bf16x8*)&As[(mi * 16 + m) * LD + ko];
#pragma unroll
    for (int mi = 0; mi < 4; ++mi)
#pragma unroll
      for (int ni = 0; ni < NI; ++ni)
        acc[mi][ni] = __builtin_amdgcn_mfma_f32_16x16x32_bf16(af[mi], bq[kc][ni], acc[mi][ni], 0, 0, 0);
  }

#pragma unroll
  for (int mi = 0; mi < 4; ++mi) {
#pragma unroll
    for (int r = 0; r < 4; ++r) {
      long grow = row0 + mi * 16 + quad * 4 + r;
      if (grow < nrows) {
#pragma unroll
        for (int ni = 0; ni < NI; ++ni) {
          long idx = grow * COLS + wcol + ni * 16 + m;
          float v = acc[mi][ni][r];
          if (panel == 0) outA[idx] = to_fp8(v);
          else            outB[idx] = (__bf16)v;
        }
      }
    }
  }
}

// ---------------- aggregation ----------------
// R10: quarter-per-node. Each 16-lane quarter owns one node; lane l owns
// channels [8l, 8l+8) for ALL edges of that node -> no cross-lane reduce,
// epilogue runs on all 64 lanes (4 nodes simultaneously). Edge indices
// preloaded 16-per-quarter with one coalesced wave load, broadcast
// per-edge via one ds_bpermute (__shfl from same-quarter lane; same exec
// group -> well-defined). 4 edges (one per quarter) per VMEM instruction.

template <bool RELU>
__global__ __launch_bounds__(256) void k_agg128(const unsigned char* __restrict__ Y,
                                                const __bf16* __restrict__ XR,
                                                const float* __restrict__ bias,
                                                const int* __restrict__ rowptr,
                                                const int* __restrict__ col,
                                                __bf16* __restrict__ out, int nnodes) {
  int wave = threadIdx.x >> 6, lane = threadIdx.x & 63;
  int quarter = lane >> 4, l = lane & 15;
  int sb = lane & 48;  // quarter * 16: bpermute source base
  int n = blockIdx.x * 16 + wave * 4 + quarter;
  bool valid = n < nnodes;
  int beg = 0, end = 0;
  if (valid) {
    beg = rowptr[n];
    end = rowptr[n + 1];
  }
  int co = l * 8;  // 8 fp8 channels per lane
  const unsigned char* Yc = Y + co;

  f32x2 av0 = {0.f, 0.f}, av1 = {0.f, 0.f}, av2 = {0.f, 0.f}, av3 = {0.f, 0.f};

  for (int base = beg; base < end; base += 16) {
    int cnt = min(end - base, 16);
    int idx = (l < cnt) ? col[base + l] : 0;  // one coalesced load / 16 edges
    int j = 0;
    for (; j + 3 < cnt; j += 4) {
      long s0 = (unsigned)__shfl(idx, sb + j);
      long s1 = (unsigned)__shfl(idx, sb + j + 1);
      long s2 = (unsigned)__shfl(idx, sb + j + 2);
      long s3 = (unsigned)__shfl(idx, sb + j + 3);
      uint2 v0 = *(const uint2*)(Yc + s0 * 128);
      uint2 v1 = *(const uint2*)(Yc + s1 * 128);
      uint2 v2 = *(const uint2*)(Yc + s2 * 128);
      uint2 v3 = *(const uint2*)(Yc + s3 * 128);
      av0 += fp8x2_lo(v0.x); av1 += fp8x2_hi(v0.x);
      av2 += fp8x2_lo(v0.y); av3 += fp8x2_hi(v0.y);
      av0 += fp8x2_lo(v1.x); av1 += fp8x2_hi(v1.x);
      av2 += fp8x2_lo(v1.y); av3 += fp8x2_hi(v1.y);
      av0 += fp8x2_lo(v2.x); av1 += fp8x2_hi(v2.x);
      av2 += fp8x2_lo(v2.y); av3 += fp8x2_hi(v2.y);
      av0 += fp8x2_lo(v3.x); av1 += fp8x2_hi(v3.x);
      av2 += fp8x2_lo(v3.y); av3 += fp8x2_hi(v3.y);
    }
    for (; j < cnt; ++j) {
      long s = (unsigned)__shfl(idx, sb + j);
      uint2 v = *(const uint2*)(Yc + s * 128);
      av0 += fp8x2_lo(v.x); av1 += fp8x2_hi(v.x);
      av2 += fp8x2_lo(v.y); av3 += fp8x2_hi(v.y);
    }
  }

  if (valid) {
    float inv = 1.f / (float)max(end - beg, 1);
    bf16x8 xv = *(const bf16x8*)(XR + (long)n * 128 + co);
    f32x4 b0 = *(const f32x4*)(bias + co);
    f32x4 b1 = *(const f32x4*)(bias + co + 4);
    float r0 = av0[0] * inv + (float)xv[0] + b0[0];
    float r1 = av0[1] * inv + (float)xv[1] + b0[1];
    float r2 = av1[0] * inv + (float)xv[2] + b0[2];
    float r3 = av1[1] * inv + (float)xv[3] + b0[3];
    float r4 = av2[0] * inv + (float)xv[4] + b1[0];
    float r5 = av2[1] * inv + (float)xv[5] + b1[1];
    float r6 = av3[0] * inv + (float)xv[6] + b1[2];
    float r7 = av3[1] * inv + (float)xv[7] + b1[3];
    if (RELU) {
      r0 = fmaxf(r0, 0.f); r1 = fmaxf(r1, 0.f);
      r2 = fmaxf(r2, 0.f); r3 = fmaxf(r3, 0.f);
      r4 = fmaxf(r4, 0.f); r5 = fmaxf(r5, 0.f);
      r6 = fmaxf(r6, 0.f); r7 = fmaxf(r7, 0.f);
    }
    bf16x8 o;
    o[0] = (__bf16)r0; o[1] = (__bf16)r1; o[2] = (__bf16)r2; o[3] = (__bf16)r3;
    o[4] = (__bf16)r4; o[5] = (__bf16)r5; o[6] = (__bf16)r6; o[7] = (__bf16)r7;
    *(bf16x8*)(out + (long)n * 128 + co) = o;
  }
}

__global__ __launch_bounds__(256) void k_agg64(const unsigned char* __restrict__ Y,
                                               const __bf16* __restrict__ XR,
                                               const float* __restrict__ bias,
                                               const int* __restrict__ rowptr,
                                               const int* __restrict__ col,
                                               float* __restrict__ out, int nnodes) {
  int wave = threadIdx.x >> 6, lane = threadIdx.x & 63;
  int quarter = lane >> 4, l = lane & 15;
  int sb = lane & 48;
  int n = blockIdx.x * 16 + wave * 4 + quarter;
  bool valid = n < nnodes;
  int beg = 0, end = 0;
  if (valid) {
    beg = rowptr[n];
    end = rowptr[n + 1];
  }
  int co = l * 4;  // 4 fp8 channels per lane
  const unsigned char* Yc = Y + co;

  f32x2 av0 = {0.f, 0.f}, av1 = {0.f, 0.f};

  for (int base = beg; base < end; base += 16) {
    int cnt = min(end - base, 16);
    int idx = (l < cnt) ? col[base + l] : 0;
    int j = 0;
    for (; j + 3 < cnt; j += 4) {
      long s0 = (unsigned)__shfl(idx, sb + j);
      long s1 = (unsigned)__shfl(idx, sb + j + 1);
      long s2 = (unsigned)__shfl(idx, sb + j + 2);
      long s3 = (unsigned)__shfl(idx, sb + j + 3);
      unsigned v0 = *(const unsigned*)(Yc + s0 * 64);
      unsigned v1 = *(const unsigned*)(Yc + s1 * 64);
      unsigned v2 = *(const unsigned*)(Yc + s2 * 64);
      unsigned v3 = *(const unsigned*)(Yc + s3 * 64);
      av0 += fp8x2_lo(v0); av1 += fp8x2_hi(v0);
      av0 += fp8x2_lo(v1); av1 += fp8x2_hi(v1);
      av0 += fp8x2_lo(v2); av1 += fp8x2_hi(v2);
      av0 += fp8x2_lo(v3); av1 += fp8x2_hi(v3);
    }
    for (; j < cnt; ++j) {
      long s = (unsigned)__shfl(idx, sb + j);
      unsigned v = *(const unsigned*)(Yc + s * 64);
      av0 += fp8x2_lo(v); av1 += fp8x2_hi(v);
    }
  }

  if (valid) {
    float inv = 1.f / (float)max(end - beg, 1);
    bf16x4 xv = *(const bf16x4*)(XR + (long)n * 64 + co);
    f32x4 bv = *(const f32x4*)(bias + co);
    f32x4 r;
    r[0] = av0[0] * inv + (float)xv[0] + bv[0];
    r[1] = av0[1] * inv + (float)xv[1] + bv[1];
    r[2] = av1[0] * inv + (float)xv[2] + bv[2];
    r[3] = av1[1] * inv + (float)xv[3] + bv[3];
    *(f32x4*)(out + (long)n * 64 + co) = r;
  }
}

// ---------------- launch ----------------

extern "C" void kernel_launch(void* const* d_in, const int* in_sizes, int n_in,
                              void* d_out, int out_size, void* d_ws, size_t ws_size,
                              hipStream_t stream) {
  const float* x   = (const float*)d_in[0];
  const int*   ei  = (const int*)d_in[1];
  const float* W1l = (const float*)d_in[2];
  const float* W1r = (const float*)d_in[3];
  const float* b1  = (const float*)d_in[4];
  const float* W2l = (const float*)d_in[5];
  const float* W2r = (const float*)d_in[6];
  const float* b2  = (const float*)d_in[7];
  float* out = (float*)d_out;

  int N = in_sizes[0] / K;   // 100000
  int E = in_sizes[1] / 2;   // 1600000
  const int* src = ei;
  const int* dst = ei + E;

  int nB = (N + 255) >> 8;          // 391 buckets
  int nblk = (E + EB - 1) / EB;     // 391 partition blocks

  char* ws = (char*)d_ws;
  size_t off = 0;
  auto alloc = [&](size_t bytes) {
    void* p = ws + off;
    off = (off + bytes + 255) & ~(size_t)255;
    return p;
  };
  int*      rowptr       = (int*)alloc(((size_t)N + 2) * 4);
  int*      col          = (int*)alloc((size_t)E * 4);
  int*      blockHist    = (int*)alloc((size_t)nblk * nB * 4);
  int*      bucketTotal  = (int*)alloc(((size_t)nB) * 4);
  int*      bucketBase   = (int*)alloc(((size_t)nB + 1) * 4);
  int*      bucketCursor = (int*)alloc((size_t)nB * 4);
  unsigned* recs         = (unsigned*)alloc((size_t)E * 4);
  unsigned char* y1      = (unsigned char*)alloc((size_t)N * 128);  // fp8
  __bf16*   xr           = (__bf16*)alloc((size_t)N * 128 * 2);
  __bf16*   h            = (__bf16*)alloc((size_t)N * 128 * 2);
  __bf16*   Bt1l         = (__bf16*)alloc((size_t)128 * K * 2);
  __bf16*   Bt1r         = (__bf16*)alloc((size_t)128 * K * 2);
  __bf16*   Bt2l         = (__bf16*)alloc((size_t)64 * K * 2);
  __bf16*   Bt2r         = (__bf16*)alloc((size_t)64 * K * 2);
  unsigned char* y2 = y1;  // layer-1 gather buffer dead after k_agg128; reuse
  __bf16*   hr = xr;

  // W pre-transpose: all 4 matrices, one launch (independent of CSR build)
  k_wprep_all<<<192, 256, 0, stream>>>(W1l, W1r, W2l, W2r, Bt1l, Bt1r, Bt2l, Bt2r);

  // CSR build (bucketed)
  hipMemsetAsync(bucketTotal, 0, (size_t)nB * 4, stream);
  k_bhist<<<nblk, 256, nB * 4, stream>>>(dst, blockHist, bucketTotal, E, N, nB);
  k_btop<<<1, 512, 0, stream>>>(bucketTotal, bucketBase, bucketCursor, nB);
  k_bscatter<<<nblk, 256, nB * 4, stream>>>(src, dst, blockHist, bucketCursor, recs, E, N, nB);
  k_bfill<<<nB, 256, 0, stream>>>(recs, bucketBase, rowptr, col, N, nB);

  int gx = (N + 63) / 64;
  // layer 1: y1 = fp8(x@W1l), xr = bf16(x@W1r); h = relu(mean(y1) + xr + b1)
  k_gemm_fused<128, float><<<gx, 512, 0, stream>>>(x, Bt1l, Bt1r, y1, xr, N);
  k_agg128<true><<<(N + 15) / 16, 256, 0, stream>>>(y1, xr, b1, rowptr, col, h, N);

  // layer 2: y2 = fp8(h@W2l), hr = bf16(h@W2r); out = mean(y2) + hr + b2
  k_gemm_fused<64, __bf16><<<gx, 512, 0, stream>>>(h, Bt2l, Bt2r, y2, hr, N);
  k_agg64<<<(N + 15) / 16, 256, 0, stream>>>(y2, hr, b2, rowptr, col, out, N);
}